// Round 1
// baseline (1905.672 us; speedup 1.0000x reference)
//
#include <hip/hip_runtime.h>
#include <math.h>

#define B_ 2
#define S_ 2048
#define D_ 512
#define H_ 8
#define DK_ 64
#define NTHREADS 256
#define CH 8   // S_ / NTHREADS

// ---------------------------------------------------------------------------
// GEMM: C[m][n] = sum_k A[m][k] * W[n][k] + bias[n]   (A: MxK, W: NxK, NT)
// scatter=1: write C to (B,H,S,DK) layout (for Q/K/V projections)
// ---------------------------------------------------------------------------
__global__ __launch_bounds__(256)
void gemm_nt(const float* __restrict__ A, const float* __restrict__ W,
             const float* __restrict__ bias, float* __restrict__ C,
             int M, int N, int K, int scatter) {
  __shared__ float As[64][17];
  __shared__ float Ws[64][17];
  const int bm = blockIdx.y * 64, bn = blockIdx.x * 64;
  const int tid = threadIdx.x;
  const int tx = tid & 15, ty = tid >> 4;
  float acc[4][4] = {};
  for (int k0 = 0; k0 < K; k0 += 16) {
#pragma unroll
    for (int l = 0; l < 4; ++l) {
      int idx = tid + l * 256;
      int r = idx >> 4, c = idx & 15;
      As[r][c] = A[(size_t)(bm + r) * K + k0 + c];
      Ws[r][c] = W[(size_t)(bn + r) * K + k0 + c];
    }
    __syncthreads();
#pragma unroll
    for (int kk = 0; kk < 16; ++kk) {
      float a[4], w[4];
#pragma unroll
      for (int u = 0; u < 4; ++u) a[u] = As[ty * 4 + u][kk];
#pragma unroll
      for (int v = 0; v < 4; ++v) w[v] = Ws[tx * 4 + v][kk];
#pragma unroll
      for (int u = 0; u < 4; ++u)
#pragma unroll
        for (int v = 0; v < 4; ++v) acc[u][v] += a[u] * w[v];
    }
    __syncthreads();
  }
#pragma unroll
  for (int u = 0; u < 4; ++u)
#pragma unroll
    for (int v = 0; v < 4; ++v) {
      int m = bm + ty * 4 + u, n = bn + tx * 4 + v;
      float val = acc[u][v] + bias[n];
      if (scatter) {
        int b = m / S_, s = m % S_;
        int h = n / DK_, d = n % DK_;
        C[(((size_t)b * H_ + h) * S_ + s) * DK_ + d] = val;
      } else {
        C[(size_t)m * N + n] = val;
      }
    }
}

// ---------------------------------------------------------------------------
// RoPE cos/sin table: cs[s*32 + i] = {cos, sin}(s * 10000^(-2i/64))
// angle rounded to f32 first (matches numpy f32 pipeline), then exact cos.
// ---------------------------------------------------------------------------
__global__ void rope_table_k(float* cs) {
  int idx = blockIdx.x * blockDim.x + threadIdx.x;
  if (idx >= S_ * 32) return;
  int s = idx >> 5, i = idx & 31;
  float invf = powf(10000.0f, -(float)(2 * i) / 64.0f);
  float ang = (float)s * invf;
  double a = (double)ang;
  cs[idx * 2]     = (float)cos(a);
  cs[idx * 2 + 1] = (float)sin(a);
}

// ---------------------------------------------------------------------------
// Apply interleaved RoPE in-place to qh and kh ((B,H,S,DK) layout)
// ---------------------------------------------------------------------------
__global__ __launch_bounds__(256)
void rope_apply_k(float* qh, float* kh, const float* __restrict__ cs) {
  size_t idx = (size_t)blockIdx.x * 256 + threadIdx.x;
  const size_t per = (size_t)B_ * H_ * S_ * 32;
  float* X = (idx < per) ? qh : kh;
  size_t r = (idx < per) ? idx : idx - per;
  int i = (int)(r & 31);
  size_t row = r >> 5;             // (b*H + h)*S + s
  int s = (int)(row & (S_ - 1));
  const float c  = cs[((size_t)s * 32 + i) * 2];
  const float sn = cs[((size_t)s * 32 + i) * 2 + 1];
  float x0 = X[row * DK_ + 2 * i];
  float x1 = X[row * DK_ + 2 * i + 1];
  X[row * DK_ + 2 * i]     = x0 * c - x1 * sn;
  X[row * DK_ + 2 * i + 1] = x1 * c + x0 * sn;
}

// ---------------------------------------------------------------------------
// Attention: one block per (b, h, query-row i).
// Two softmaxes + cumsum-based distance decay, then PV.
// ---------------------------------------------------------------------------
__global__ __launch_bounds__(256)
void attn_k(const float* __restrict__ qh, const float* __restrict__ kh,
            const float* __restrict__ vh, const float* __restrict__ gammas,
            float* __restrict__ out_pre) {
  const int bid = blockIdx.x;
  const int i  = bid & (S_ - 1);
  const int bh = bid >> 11;        // S_ = 2^11
  const int h  = bh & (H_ - 1);
  const int b  = bh >> 3;          // H_ = 8
  const int tid = threadIdx.x;

  float* outp = out_pre + ((size_t)b * S_ + i) * D_ + h * DK_;

  if (i == 0) {                    // shift_down zeroes row 0 of attention
    if (tid < DK_) outp[tid] = 0.0f;
    return;
  }

  __shared__ float qv[DK_];
  __shared__ float red[NTHREADS];
  __shared__ float csum[NTHREADS];
  __shared__ float pw[S_];

  const float* qrow = qh + ((size_t)bh * S_ + i) * DK_;
  if (tid < DK_) qv[tid] = qrow[tid];
  __syncthreads();

  const float* Kp = kh + (size_t)bh * S_ * DK_;
  const float* Vp = vh + (size_t)bh * S_ * DK_;

  const int j0 = tid * CH;
  float sc[CH], pex[CH];

  // Phase A: raw scores (j <= i), block max
  float lmax = -INFINITY;
  const float4* qv4 = reinterpret_cast<const float4*>(qv);
#pragma unroll
  for (int c = 0; c < CH; ++c) {
    int j = j0 + c;
    if (j <= i) {
      const float4* kr = reinterpret_cast<const float4*>(Kp + (size_t)j * DK_);
      float dot = 0.f;
#pragma unroll
      for (int d = 0; d < DK_ / 4; ++d) {
        float4 kv = kr[d]; float4 qq = qv4[d];
        dot += kv.x * qq.x + kv.y * qq.y + kv.z * qq.z + kv.w * qq.w;
      }
      sc[c] = dot * 0.125f;        // 1/sqrt(64)
      lmax = fmaxf(lmax, sc[c]);
    } else {
      sc[c] = -INFINITY;
    }
  }
  red[tid] = lmax; __syncthreads();
  for (int s = 128; s > 0; s >>= 1) {
    if (tid < s) red[tid] = fmaxf(red[tid], red[tid + s]);
    __syncthreads();
  }
  const float m1 = red[0];
  __syncthreads();

  // exp + block sum (first softmax denominator)
  float lsum = 0.f;
#pragma unroll
  for (int c = 0; c < CH; ++c) {
    float e = (j0 + c <= i) ? expf(sc[c] - m1) : 0.f;
    pex[c] = e; lsum += e;
  }
  red[tid] = lsum; __syncthreads();
  for (int s = 128; s > 0; s >>= 1) {
    if (tid < s) red[tid] += red[tid + s];
    __syncthreads();
  }
  const float denom = red[0];
  __syncthreads();
  const float inv = 1.0f / denom;

  // block-wide inclusive scan of per-thread exp-sums (for cumsum)
  csum[tid] = lsum; __syncthreads();
  for (int off = 1; off < NTHREADS; off <<= 1) {
    float v = (tid >= off) ? csum[tid - off] : 0.f;
    __syncthreads();
    if (tid >= off) csum[tid] += v;
    __syncthreads();
  }
  float run = (tid > 0) ? csum[tid - 1] : 0.f;   // exclusive prefix

  const float gamma = gammas[h * S_ + i];
  const float g = -log1pf(expf(gamma));          // -softplus

  // Phase B: distance-decayed scores, second max
  float l2max = -INFINITY;
#pragma unroll
  for (int c = 0; c < CH; ++c) {
    int j = j0 + c;
    if (j <= i) {
      run += pex[c];
      float rem = 1.0f - run * inv;              // disttot - distcum
      float dist = sqrtf(fmaxf(rem * (float)(i - j), 0.f));
      float te = expf(dist * g);
      te = fminf(fmaxf(te, 1e-5f), 1e5f);
      sc[c] = te * sc[c];
      l2max = fmaxf(l2max, sc[c]);
    }
  }
  red[tid] = l2max; __syncthreads();
  for (int s = 128; s > 0; s >>= 1) {
    if (tid < s) red[tid] = fmaxf(red[tid], red[tid + s]);
    __syncthreads();
  }
  const float m2 = red[0];
  __syncthreads();

  // second softmax
  float l2sum = 0.f;
#pragma unroll
  for (int c = 0; c < CH; ++c) {
    float e = (j0 + c <= i) ? expf(sc[c] - m2) : 0.f;
    pex[c] = e; l2sum += e;
  }
  red[tid] = l2sum; __syncthreads();
  for (int s = 128; s > 0; s >>= 1) {
    if (tid < s) red[tid] += red[tid + s];
    __syncthreads();
  }
  const float inv2 = 1.0f / red[0];
  __syncthreads();

#pragma unroll
  for (int c = 0; c < CH; ++c) pw[j0 + c] = pex[c] * inv2;
  __syncthreads();

  // Phase C: out[d] = sum_j pw[j] * V[j][d]
  const int d  = tid & 63;
  const int jg = tid >> 6;                        // 4 j-groups (one per wave)
  float acc = 0.f;
  for (int j = jg; j <= i; j += 4)
    acc += pw[j] * Vp[(size_t)j * DK_ + d];
  red[tid] = acc; __syncthreads();
  if (tid < 128) red[tid] += red[tid + 128];
  __syncthreads();
  if (tid < 64) outp[tid] = red[tid] + red[tid + 64];
}

// ---------------------------------------------------------------------------
extern "C" void kernel_launch(void* const* d_in, const int* in_sizes, int n_in,
                              void* d_out, int out_size, void* d_ws, size_t ws_size,
                              hipStream_t stream) {
  const float* q  = (const float*)d_in[0];
  const float* k  = (const float*)d_in[1];
  const float* v  = (const float*)d_in[2];
  // d_in[3] = ltime (unused), d_in[4] = mask (deterministic causal, unused)
  const float* Wq = (const float*)d_in[5];
  const float* bq = (const float*)d_in[6];
  const float* Wk = (const float*)d_in[7];
  const float* bk = (const float*)d_in[8];
  const float* Wv = (const float*)d_in[9];
  const float* bv = (const float*)d_in[10];
  const float* Wo = (const float*)d_in[11];
  const float* bo = (const float*)d_in[12];
  const float* gammas = (const float*)d_in[13];
  float* out = (float*)d_out;

  // workspace layout (floats); total ~34 MB
  float* ws = (float*)d_ws;
  const size_t nBHSD = (size_t)B_ * H_ * S_ * DK_;   // 2,097,152
  float* qh = ws;
  float* kh = qh + nBHSD;
  float* vh = kh + nBHSD;
  float* out_pre = vh + nBHSD;                        // (B,S,D)
  float* cs = out_pre + (size_t)B_ * S_ * D_;         // S*32*2

  const int M = B_ * S_;   // 4096
  dim3 gg(D_ / 64, M / 64);

  gemm_nt<<<gg, 256, 0, stream>>>(q, Wq, bq, qh, M, D_, D_, 1);
  gemm_nt<<<gg, 256, 0, stream>>>(k, Wk, bk, kh, M, D_, D_, 1);
  gemm_nt<<<gg, 256, 0, stream>>>(v, Wv, bv, vh, M, D_, D_, 1);

  rope_table_k<<<(S_ * 32 + 255) / 256, 256, 0, stream>>>(cs);

  const size_t nPairs = 2 * (size_t)B_ * H_ * S_ * 32;
  rope_apply_k<<<(unsigned)(nPairs / 256), 256, 0, stream>>>(qh, kh, cs);

  attn_k<<<B_ * H_ * S_, NTHREADS, 0, stream>>>(qh, kh, vh, gammas, out_pre);

  gemm_nt<<<gg, 256, 0, stream>>>(out_pre, Wo, bo, out, M, D_, D_, 0);
}

// Round 3
// 670.397 us; speedup vs baseline: 2.8426x; 2.8426x over previous
//
#include <hip/hip_runtime.h>
#include <math.h>

#define B_ 2
#define S_ 2048
#define D_ 512
#define H_ 8
#define DK_ 64
#define QT 64     // query rows per attention block
#define JT 32     // key tile

typedef __attribute__((ext_vector_type(8))) short bf16x8;
typedef __attribute__((ext_vector_type(4))) float f32x4;

__device__ inline unsigned short f2bf(float x) {
  unsigned u = __float_as_uint(x);
  unsigned r = (u + 0x7fffu + ((u >> 16) & 1u)) >> 16;
  return (unsigned short)r;
}

__device__ inline float rmax16(float v) {
  v = fmaxf(v, __shfl_xor(v, 1, 64));
  v = fmaxf(v, __shfl_xor(v, 2, 64));
  v = fmaxf(v, __shfl_xor(v, 4, 64));
  v = fmaxf(v, __shfl_xor(v, 8, 64));
  return v;
}
__device__ inline float rsum16(float v) {
  v += __shfl_xor(v, 1, 64);
  v += __shfl_xor(v, 2, 64);
  v += __shfl_xor(v, 4, 64);
  v += __shfl_xor(v, 8, 64);
  return v;
}
// inclusive prefix sum across each 16-lane group (col order = lane&15)
__device__ inline float scan16(float v, int lane) {
#pragma unroll
  for (int off = 1; off < 16; off <<= 1) {
    int src = lane - off; if (src < 0) src = 0;
    float x = __shfl(v, src, 64);
    if ((lane & 15) >= off) v += x;
  }
  return v;
}

// ---------------------------------------------------------------------------
// RoPE cos/sin table: cs[(s*32+i)*2 + {0,1}] = cos/sin(s * 10000^(-2i/64))
// ---------------------------------------------------------------------------
__global__ void rope_table_k(float* cs) {
  int idx = blockIdx.x * blockDim.x + threadIdx.x;
  if (idx >= S_ * 32) return;
  int s = idx >> 5, i = idx & 31;
  float invf = powf(10000.0f, -(float)(2 * i) / 64.0f);
  float ang = (float)s * invf;
  double a = (double)ang;
  cs[idx * 2]     = (float)cos(a);
  cs[idx * 2 + 1] = (float)sin(a);
}

// ---------------------------------------------------------------------------
// GEMM: C = A(MxK) * W(NxK)^T + bias, fp32.
// mode 0: plain f32 row-major out (MxN)
// mode 1: fused RoPE + bf16, scatter to (B,H,S,DK) panel
// mode 2: bf16, scatter transposed to (B,H,DK,S) panel (for V)
// ---------------------------------------------------------------------------
__global__ __launch_bounds__(256)
void gemm_nt(const float* __restrict__ A, const float* __restrict__ W,
             const float* __restrict__ bias, void* __restrict__ Cout,
             const float* __restrict__ cs, int M, int N, int K, int mode) {
  __shared__ float As[64][17];
  __shared__ float Ws[64][17];
  const int bm = blockIdx.y * 64, bn = blockIdx.x * 64;
  const int tid = threadIdx.x;
  const int tx = tid & 15, ty = tid >> 4;
  float acc[4][4] = {};
  for (int k0 = 0; k0 < K; k0 += 16) {
#pragma unroll
    for (int l = 0; l < 4; ++l) {
      int idx = tid + l * 256;
      int r = idx >> 4, c = idx & 15;
      As[r][c] = A[(size_t)(bm + r) * K + k0 + c];
      Ws[r][c] = W[(size_t)(bn + r) * K + k0 + c];
    }
    __syncthreads();
#pragma unroll
    for (int kk = 0; kk < 16; ++kk) {
      float a[4], w[4];
#pragma unroll
      for (int u = 0; u < 4; ++u) a[u] = As[ty * 4 + u][kk];
#pragma unroll
      for (int v = 0; v < 4; ++v) w[v] = Ws[tx * 4 + v][kk];
#pragma unroll
      for (int u = 0; u < 4; ++u)
#pragma unroll
        for (int v = 0; v < 4; ++v) acc[u][v] += a[u] * w[v];
    }
    __syncthreads();
  }
  const int m0 = bm + ty * 4, n0 = bn + tx * 4;
  if (mode == 0) {
    float* C = (float*)Cout;
#pragma unroll
    for (int u = 0; u < 4; ++u)
#pragma unroll
      for (int v = 0; v < 4; ++v)
        C[(size_t)(m0 + u) * N + n0 + v] = acc[u][v] + bias[n0 + v];
  } else if (mode == 1) {
    unsigned short* C = (unsigned short*)Cout;
    const int d = tx * 4;                 // n0 % 64 (bn is a multiple of 64)
    const int h = n0 >> 6;
#pragma unroll
    for (int u = 0; u < 4; ++u) {
      int mm = m0 + u, b = mm >> 11, s = mm & (S_ - 1);
      const float* cp = cs + ((size_t)s * 32 + (d >> 1)) * 2;
      float c0 = cp[0], s0 = cp[1], c1 = cp[2], s1 = cp[3];
      float x0 = acc[u][0] + bias[n0];
      float x1 = acc[u][1] + bias[n0 + 1];
      float x2 = acc[u][2] + bias[n0 + 2];
      float x3 = acc[u][3] + bias[n0 + 3];
      unsigned short* dst = C + ((((size_t)b * H_ + h) * S_ + s) * DK_) + d;
      dst[0] = f2bf(x0 * c0 - x1 * s0);
      dst[1] = f2bf(x1 * c0 + x0 * s0);
      dst[2] = f2bf(x2 * c1 - x3 * s1);
      dst[3] = f2bf(x3 * c1 + x2 * s1);
    }
  } else {
    unsigned short* C = (unsigned short*)Cout;
#pragma unroll
    for (int u = 0; u < 4; ++u)
#pragma unroll
      for (int v = 0; v < 4; ++v) {
        int mm = m0 + u, nn = n0 + v;
        int b = mm >> 11, s = mm & (S_ - 1), h = nn >> 6, d = nn & 63;
        C[(((size_t)b * H_ + h) * DK_ + d) * S_ + s] = f2bf(acc[u][v] + bias[nn]);
      }
  }
}

// ---------------------------------------------------------------------------
// MFMA attention: block = (b,h, 64 query rows), 4 waves x 16 rows each.
// Pass 1: exact softmax-1 stats. Pass 2: cumsum decay + online softmax-2 + PV.
// ---------------------------------------------------------------------------
__global__ __launch_bounds__(256)
void attn_mfma(const unsigned short* __restrict__ Qbf,
               const unsigned short* __restrict__ Kbf,
               const unsigned short* __restrict__ Vtbf,
               const float* __restrict__ gammas,
               float* __restrict__ out_pre) {
  const int qt = 31 - blockIdx.x;          // big blocks dispatched first
  const int bh = blockIdx.y;
  const int h = bh & (H_ - 1), b = bh >> 3;
  const int i0 = qt * QT;
  const int tid = threadIdx.x;
  const int w = tid >> 6, lane = tid & 63;
  const int li = lane & 15, lg = lane >> 4;

  __shared__ __align__(16) unsigned short Klds[32][72];    // 144B rows
  __shared__ __align__(16) unsigned short Vtlds[64][40];   // 80B rows
  __shared__ __align__(16) unsigned short Plds[4][16][40];

  const unsigned short* Qp = Qbf + (size_t)bh * S_ * DK_;
  const unsigned short* Kp = Kbf + (size_t)bh * S_ * DK_;
  const unsigned short* Vp = Vtbf + (size_t)bh * DK_ * S_;

  const int rowbase = i0 + w * 16;
  const int myrows_max = rowbase + 15;

  // Q A-fragments (row = lane&15, k = (lane>>4)*8 + e), two K-halves
  bf16x8 qa0 = *(const bf16x8*)(Qp + (size_t)(rowbase + li) * DK_ + lg * 8);
  bf16x8 qa1 = *(const bf16x8*)(Qp + (size_t)(rowbase + li) * DK_ + 32 + lg * 8);

  float m1[4], denom[4];
#pragma unroll
  for (int r = 0; r < 4; ++r) { m1[r] = -INFINITY; denom[r] = 0.f; }

  const int ntile = (i0 + QT) / JT;

  // ---------------- pass 1: softmax-1 stats ----------------
  for (int jt = 0; jt < ntile; ++jt) {
    const int j0 = jt * JT;
    __syncthreads();
    { // stage K tile (contiguous 4KB)
      uint4 kv = *(const uint4*)(Kp + (size_t)j0 * DK_ + tid * 8);
      *(uint4*)&Klds[tid >> 3][(tid & 7) * 8] = kv;
    }
    __syncthreads();
    if (j0 > myrows_max) continue;

    f32x4 acc0 = {0.f,0.f,0.f,0.f}, acc1 = {0.f,0.f,0.f,0.f};
    {
      bf16x8 kb00 = *(const bf16x8*)&Klds[li][lg * 8];
      bf16x8 kb01 = *(const bf16x8*)&Klds[li][32 + lg * 8];
      bf16x8 kb10 = *(const bf16x8*)&Klds[16 + li][lg * 8];
      bf16x8 kb11 = *(const bf16x8*)&Klds[16 + li][32 + lg * 8];
      acc0 = __builtin_amdgcn_mfma_f32_16x16x32_bf16(qa0, kb00, acc0, 0, 0, 0);
      acc0 = __builtin_amdgcn_mfma_f32_16x16x32_bf16(qa1, kb01, acc0, 0, 0, 0);
      acc1 = __builtin_amdgcn_mfma_f32_16x16x32_bf16(qa0, kb10, acc1, 0, 0, 0);
      acc1 = __builtin_amdgcn_mfma_f32_16x16x32_bf16(qa1, kb11, acc1, 0, 0, 0);
    }
#pragma unroll
    for (int r = 0; r < 4; ++r) {
      const int i = rowbase + lg * 4 + r;
      float s0 = acc0[r] * 0.125f, s1 = acc1[r] * 0.125f;
      bool u0 = (j0 + li) <= i, u1 = (j0 + 16 + li) <= i;
      float tm = rmax16(fmaxf(u0 ? s0 : -INFINITY, u1 ? s1 : -INFINITY));
      float mn = fmaxf(m1[r], tm);
      float p0 = u0 ? expf(s0 - mn) : 0.f;
      float p1 = u1 ? expf(s1 - mn) : 0.f;
      float ts = rsum16(p0 + p1);
      denom[r] = denom[r] * expf(m1[r] - mn) + ts;
      m1[r] = mn;
    }
  }

  float inv1[4], g[4];
#pragma unroll
  for (int r = 0; r < 4; ++r) {
    inv1[r] = 1.0f / denom[r];
    const int i = rowbase + lg * 4 + r;
    float gm = gammas[h * S_ + i];
    g[r] = -log1pf(expf(gm));              // -softplus(gamma)
  }

  // ---------------- pass 2: decay + softmax-2 + PV ----------------
  f32x4 o0 = {0.f,0.f,0.f,0.f}, o1 = {0.f,0.f,0.f,0.f};
  f32x4 o2 = {0.f,0.f,0.f,0.f}, o3 = {0.f,0.f,0.f,0.f};
  float cum[4] = {0.f,0.f,0.f,0.f}, m2[4], l2[4] = {0.f,0.f,0.f,0.f};
#pragma unroll
  for (int r = 0; r < 4; ++r) m2[r] = -INFINITY;

  for (int jt = 0; jt < ntile; ++jt) {
    const int j0 = jt * JT;
    __syncthreads();
    { // stage K + Vt tiles
      uint4 kv = *(const uint4*)(Kp + (size_t)j0 * DK_ + tid * 8);
      *(uint4*)&Klds[tid >> 3][(tid & 7) * 8] = kv;
      uint4 vv = *(const uint4*)(Vp + (size_t)(tid >> 2) * S_ + j0 + (tid & 3) * 8);
      *(uint4*)&Vtlds[tid >> 2][(tid & 3) * 8] = vv;
    }
    __syncthreads();
    if (j0 > myrows_max) continue;

    f32x4 acc0 = {0.f,0.f,0.f,0.f}, acc1 = {0.f,0.f,0.f,0.f};
    {
      bf16x8 kb00 = *(const bf16x8*)&Klds[li][lg * 8];
      bf16x8 kb01 = *(const bf16x8*)&Klds[li][32 + lg * 8];
      bf16x8 kb10 = *(const bf16x8*)&Klds[16 + li][lg * 8];
      bf16x8 kb11 = *(const bf16x8*)&Klds[16 + li][32 + lg * 8];
      acc0 = __builtin_amdgcn_mfma_f32_16x16x32_bf16(qa0, kb00, acc0, 0, 0, 0);
      acc0 = __builtin_amdgcn_mfma_f32_16x16x32_bf16(qa1, kb01, acc0, 0, 0, 0);
      acc1 = __builtin_amdgcn_mfma_f32_16x16x32_bf16(qa0, kb10, acc1, 0, 0, 0);
      acc1 = __builtin_amdgcn_mfma_f32_16x16x32_bf16(qa1, kb11, acc1, 0, 0, 0);
    }

#pragma unroll
    for (int r = 0; r < 4; ++r) {
      const int i = rowbase + lg * 4 + r;
      float s0 = acc0[r] * 0.125f, s1 = acc1[r] * 0.125f;
      bool u0 = (j0 + li) <= i, u1 = (j0 + 16 + li) <= i;
      // softmax-1 probabilities (unnormalized) + running cumsum
      float e0 = u0 ? expf(s0 - m1[r]) : 0.f;
      float e1 = u1 ? expf(s1 - m1[r]) : 0.f;
      float pre0 = scan16(e0, lane);
      float tot0 = __shfl(pre0, (lane & 48) | 15, 64);
      float pre1 = scan16(e1, lane) + tot0;
      float ttot = __shfl(pre1, (lane & 48) | 15, 64);
      float c0v = cum[r] + pre0, c1v = cum[r] + pre1;
      cum[r] += ttot;
      // distance decay
      float rem0 = fmaxf(1.f - c0v * inv1[r], 0.f);
      float rem1 = fmaxf(1.f - c1v * inv1[r], 0.f);
      float pos0 = fabsf((float)(i - (j0 + li)));
      float pos1 = fabsf((float)(i - (j0 + 16 + li)));
      float t0 = fminf(fmaxf(expf(sqrtf(rem0 * pos0) * g[r]), 1e-5f), 1e5f);
      float t1 = fminf(fmaxf(expf(sqrtf(rem1 * pos1) * g[r]), 1e-5f), 1e5f);
      float s2_0 = u0 ? t0 * s0 : -INFINITY;
      float s2_1 = u1 ? t1 * s1 : -INFINITY;
      // online softmax-2
      float tm = rmax16(fmaxf(s2_0, s2_1));
      float mn = fmaxf(m2[r], tm);
      float f = expf(m2[r] - mn);
      float p0 = expf(s2_0 - mn);
      float p1 = expf(s2_1 - mn);
      l2[r] = l2[r] * f + rsum16(p0 + p1);
      m2[r] = mn;
      o0[r] *= f; o1[r] *= f; o2[r] *= f; o3[r] *= f;
      Plds[w][lg * 4 + r][li]      = f2bf(p0);
      Plds[w][lg * 4 + r][16 + li] = f2bf(p1);
    }
    // PV: A = P (row=li, k=lg*8+e), B = V via transposed LDS tile
    bf16x8 pa  = *(const bf16x8*)&Plds[w][li][lg * 8];
    bf16x8 vb0 = *(const bf16x8*)&Vtlds[li][lg * 8];
    bf16x8 vb1 = *(const bf16x8*)&Vtlds[16 + li][lg * 8];
    bf16x8 vb2 = *(const bf16x8*)&Vtlds[32 + li][lg * 8];
    bf16x8 vb3 = *(const bf16x8*)&Vtlds[48 + li][lg * 8];
    o0 = __builtin_amdgcn_mfma_f32_16x16x32_bf16(pa, vb0, o0, 0, 0, 0);
    o1 = __builtin_amdgcn_mfma_f32_16x16x32_bf16(pa, vb1, o1, 0, 0, 0);
    o2 = __builtin_amdgcn_mfma_f32_16x16x32_bf16(pa, vb2, o2, 0, 0, 0);
    o3 = __builtin_amdgcn_mfma_f32_16x16x32_bf16(pa, vb3, o3, 0, 0, 0);
  }

  // epilogue: normalize + write (zero global row 0 == shift_down)
#pragma unroll
  for (int r = 0; r < 4; ++r) {
    const int i = rowbase + lg * 4 + r;
    float z = (i == 0) ? 0.f : (1.0f / l2[r]);
    float* dst = out_pre + ((size_t)b * S_ + i) * D_ + h * DK_;
    dst[li]      = o0[r] * z;
    dst[16 + li] = o1[r] * z;
    dst[32 + li] = o2[r] * z;
    dst[48 + li] = o3[r] * z;
  }
}

// ---------------------------------------------------------------------------
extern "C" void kernel_launch(void* const* d_in, const int* in_sizes, int n_in,
                              void* d_out, int out_size, void* d_ws, size_t ws_size,
                              hipStream_t stream) {
  const float* q  = (const float*)d_in[0];
  const float* k  = (const float*)d_in[1];
  const float* v  = (const float*)d_in[2];
  const float* Wq = (const float*)d_in[5];
  const float* bq = (const float*)d_in[6];
  const float* Wk = (const float*)d_in[7];
  const float* bk = (const float*)d_in[8];
  const float* Wv = (const float*)d_in[9];
  const float* bv = (const float*)d_in[10];
  const float* Wo = (const float*)d_in[11];
  const float* bo = (const float*)d_in[12];
  const float* gammas = (const float*)d_in[13];
  float* out = (float*)d_out;

  // workspace: out_pre(8MB) | cs(512KB) | Qbf/Kbf/Vtbf (4MB each) = ~21MB
  float* out_pre = (float*)d_ws;
  float* cs = out_pre + (size_t)B_ * S_ * D_;
  unsigned short* Qbf  = (unsigned short*)(cs + (size_t)S_ * 32 * 2);
  unsigned short* Kbf  = Qbf + (size_t)B_ * H_ * S_ * DK_;
  unsigned short* Vtbf = Kbf + (size_t)B_ * H_ * S_ * DK_;

  const int M = B_ * S_;
  dim3 gg(D_ / 64, M / 64);

  rope_table_k<<<(S_ * 32 + 255) / 256, 256, 0, stream>>>(cs);

  gemm_nt<<<gg, 256, 0, stream>>>(q, Wq, bq, Qbf,  cs, M, D_, D_, 1);
  gemm_nt<<<gg, 256, 0, stream>>>(k, Wk, bk, Kbf,  cs, M, D_, D_, 1);
  gemm_nt<<<gg, 256, 0, stream>>>(v, Wv, bv, Vtbf, cs, M, D_, D_, 2);

  attn_mfma<<<dim3(S_ / QT, B_ * H_), 256, 0, stream>>>(Qbf, Kbf, Vtbf, gammas, out_pre);

  gemm_nt<<<gg, 256, 0, stream>>>(out_pre, Wo, bo, out, nullptr, M, D_, D_, 0);
}

// Round 5
// 438.882 us; speedup vs baseline: 4.3421x; 1.5275x over previous
//
#include <hip/hip_runtime.h>
#include <math.h>

#define B_ 2
#define S_ 2048
#define D_ 512
#define H_ 8
#define DK_ 64

typedef __attribute__((ext_vector_type(8))) short bf16x8;
typedef __attribute__((ext_vector_type(4))) float f32x4;

#define MFMA16(A, Bv, C) __builtin_amdgcn_mfma_f32_16x16x32_bf16(A, Bv, C, 0, 0, 0)

__device__ inline unsigned short f2bf(float x) {
  unsigned u = __float_as_uint(x);
  unsigned r = (u + 0x7fffu + ((u >> 16) & 1u)) >> 16;
  return (unsigned short)r;
}
__device__ inline unsigned pack2(float a, float b) {
  return (unsigned)f2bf(a) | ((unsigned)f2bf(b) << 16);
}

// ---------------------------------------------------------------------------
// RoPE cos/sin table: cs[(s*32+i)*2 + {0,1}]
// ---------------------------------------------------------------------------
__global__ void rope_table_k(float* cs) {
  int idx = blockIdx.x * blockDim.x + threadIdx.x;
  if (idx >= S_ * 32) return;
  int s = idx >> 5, i = idx & 31;
  float invf = powf(10000.0f, -(float)(2 * i) / 64.0f);
  float ang = (float)s * invf;
  double a = (double)ang;
  cs[idx * 2]     = (float)cos(a);
  cs[idx * 2 + 1] = (float)sin(a);
}

// ---------------------------------------------------------------------------
// f32 -> bf16 converters (vectorized, 4 elems/thread)
// ---------------------------------------------------------------------------
__global__ __launch_bounds__(256)
void cvt3_k(const float* __restrict__ a, const float* __restrict__ b,
            const float* __restrict__ c, unsigned short* __restrict__ dst) {
  size_t idx = ((size_t)blockIdx.x * 256 + threadIdx.x) * 4;
  const size_t per = (size_t)4096 * 512;
  const float* src; size_t r;
  if (idx < per)            { src = a; r = idx; }
  else if (idx < 2 * per)   { src = b; r = idx - per; }
  else                      { src = c; r = idx - 2 * per; }
  float4 x = *(const float4*)(src + r);
  ushort4 y = { f2bf(x.x), f2bf(x.y), f2bf(x.z), f2bf(x.w) };
  *(ushort4*)(dst + idx) = y;
}
__global__ __launch_bounds__(256)
void cvt4_k(const float* __restrict__ a, const float* __restrict__ b,
            const float* __restrict__ c, const float* __restrict__ d,
            unsigned short* __restrict__ dst) {
  size_t idx = ((size_t)blockIdx.x * 256 + threadIdx.x) * 4;
  const size_t per = (size_t)512 * 512;
  const float* src; size_t r;
  if (idx < per)            { src = a; r = idx; }
  else if (idx < 2 * per)   { src = b; r = idx - per; }
  else if (idx < 3 * per)   { src = c; r = idx - 2 * per; }
  else                      { src = d; r = idx - 3 * per; }
  float4 x = *(const float4*)(src + r);
  ushort4 y = { f2bf(x.x), f2bf(x.y), f2bf(x.z), f2bf(x.w) };
  *(ushort4*)(dst + idx) = y;
}

// ---------------------------------------------------------------------------
// bf16 MFMA GEMM: C = A(Mx512) * W(512x512)^T + bias
// tile 64x64, 4 waves (wave w owns cols w*16..w*16+15), BK=64
// mode 0: f32 out [M][512]; mode 1: RoPE+bf16 -> (B,H,S,DK);
// mode 2: bf16 -> (B,H,DK,S) transposed (V)
// ---------------------------------------------------------------------------
__global__ __launch_bounds__(256)
void gemm_bf(const unsigned short* __restrict__ A,
             const unsigned short* __restrict__ W,
             const float* __restrict__ bias, void* __restrict__ Cout,
             const float* __restrict__ cs, int mode) {
  const int bm = blockIdx.y * 64, bn = blockIdx.x * 64;
  const int tid = threadIdx.x, w = tid >> 6, lane = tid & 63;
  const int li = lane & 15, lg = lane >> 4;
  __shared__ __align__(16) unsigned short As[64 * 64];
  __shared__ __align__(16) unsigned short Ws[64 * 64];
  f32x4 acc[4] = {{0.f,0.f,0.f,0.f},{0.f,0.f,0.f,0.f},{0.f,0.f,0.f,0.f},{0.f,0.f,0.f,0.f}};

  const int Bo0 = tid * 16, Bo1 = tid * 16 + 4096;
  const int r0 = Bo0 >> 7, c0 = Bo0 & 127;     // tile row / col-byte
  const int r1 = Bo1 >> 7, c1 = Bo1 & 127;
  const int so0 = (r0 * 128 + (c0 ^ ((r0 & 7) << 4))) >> 1;  // swizzled dest (ushort idx)
  const int so1 = (r1 * 128 + (c1 ^ ((r1 & 7) << 4))) >> 1;

  const char* Abase = (const char*)A;
  const char* Wbase = (const char*)W;
  uint4 ra0 = *(const uint4*)(Abase + (size_t)(bm + r0) * 1024 + c0);
  uint4 ra1 = *(const uint4*)(Abase + (size_t)(bm + r1) * 1024 + c1);
  uint4 rw0 = *(const uint4*)(Wbase + (size_t)(bn + r0) * 1024 + c0);
  uint4 rw1 = *(const uint4*)(Wbase + (size_t)(bn + r1) * 1024 + c1);

  for (int t = 0; t < 8; ++t) {
    __syncthreads();                      // previous iter's ds_reads done
    *(uint4*)&As[so0] = ra0; *(uint4*)&As[so1] = ra1;
    *(uint4*)&Ws[so0] = rw0; *(uint4*)&Ws[so1] = rw1;
    __syncthreads();
    if (t < 7) {                          // prefetch next K-slab
      int k0 = (t + 1) * 128;             // byte offset = k*2
      ra0 = *(const uint4*)(Abase + (size_t)(bm + r0) * 1024 + k0 + c0);
      ra1 = *(const uint4*)(Abase + (size_t)(bm + r1) * 1024 + k0 + c1);
      rw0 = *(const uint4*)(Wbase + (size_t)(bn + r0) * 1024 + k0 + c0);
      rw1 = *(const uint4*)(Wbase + (size_t)(bn + r1) * 1024 + k0 + c1);
    }
#pragma unroll
    for (int kk = 0; kk < 2; ++kk) {
      const int brow = w * 16 + li;
      bf16x8 bf = *(const bf16x8*)&Ws[brow * 64 + (((kk * 64 + lg * 16) ^ ((brow & 7) << 4)) >> 1)];
#pragma unroll
      for (int mt = 0; mt < 4; ++mt) {
        const int arow = mt * 16 + li;
        bf16x8 af = *(const bf16x8*)&As[arow * 64 + (((kk * 64 + lg * 16) ^ ((arow & 7) << 4)) >> 1)];
        acc[mt] = MFMA16(af, bf, acc[mt]);
      }
    }
  }

  const int n = bn + w * 16 + li;
  const float bv = bias[n];
  if (mode == 0) {
    float* C = (float*)Cout;
#pragma unroll
    for (int mt = 0; mt < 4; ++mt)
#pragma unroll
      for (int r = 0; r < 4; ++r) {
        int m = bm + mt * 16 + lg * 4 + r;
        C[(size_t)m * 512 + n] = acc[mt][r] + bv;
      }
  } else if (mode == 1) {
    unsigned short* C = (unsigned short*)Cout;
    const int d = n & 63, hh = n >> 6, p = d >> 1;
#pragma unroll
    for (int mt = 0; mt < 4; ++mt)
#pragma unroll
      for (int r = 0; r < 4; ++r) {
        int m = bm + mt * 16 + lg * 4 + r;
        int bb = m >> 11, sp = m & (S_ - 1);
        float val = acc[mt][r] + bv;
        float other = __shfl_xor(val, 1, 64);
        const float* cp = cs + ((size_t)sp * 32 + p) * 2;
        float cc = cp[0], sn = cp[1];
        float y = (d & 1) ? (val * cc + other * sn) : (val * cc - other * sn);
        C[(((size_t)bb * H_ + hh) * S_ + sp) * DK_ + d] = f2bf(y);
      }
  } else {
    unsigned short* C = (unsigned short*)Cout;
    const int d = n & 63, hh = n >> 6;
#pragma unroll
    for (int mt = 0; mt < 4; ++mt) {
      int m0 = bm + mt * 16 + lg * 4;
      int bb = m0 >> 11, sp0 = m0 & (S_ - 1);
      ushort4 y = { f2bf(acc[mt][0] + bv), f2bf(acc[mt][1] + bv),
                    f2bf(acc[mt][2] + bv), f2bf(acc[mt][3] + bv) };
      *(ushort4*)&C[(((size_t)bb * H_ + hh) * DK_ + d) * S_ + sp0] = y;
    }
  }
}

// ---------------------------------------------------------------------------
// Barrier-free 1-wave attention, swapped QK^T (keys in regs, query = lane&15)
// block = 64 threads = 1 wave = 16 query rows; grid (128, B*H)
// ---------------------------------------------------------------------------
__global__ __launch_bounds__(64)
void attn2(const unsigned short* __restrict__ Qbf,
           const unsigned short* __restrict__ Kbf,
           const unsigned short* __restrict__ Vtbf,
           const float* __restrict__ gammas,
           unsigned short* __restrict__ out_pre) {
  const int qt = 127 - (int)blockIdx.x;     // big blocks first
  const int bh = blockIdx.y;
  const int h = bh & (H_ - 1), b = bh >> 3;
  const int i0 = qt * 16;
  const int lane = threadIdx.x;
  const int li = lane & 15, lg = lane >> 4;
  const int i = i0 + li;                    // this lane's query row

  __shared__ __align__(16) unsigned short P[16][40];   // 1.25KB P-bounce

  const unsigned short* Qp = Qbf + (size_t)bh * (S_ * DK_);
  const unsigned short* Kp = Kbf + (size_t)bh * (S_ * DK_);
  const unsigned short* Vp = Vtbf + (size_t)bh * (DK_ * S_);

  // Q as B-operand: n = li = query row, k = lg*8+e
  bf16x8 qb0 = *(const bf16x8*)(Qp + (size_t)i * DK_ + lg * 8);
  bf16x8 qb1 = *(const bf16x8*)(Qp + (size_t)i * DK_ + 32 + lg * 8);

  const int ntile = (i0 >> 5) + 1;          // 32-key tiles covering 0..i0+15
  const float g = -log1pf(expf(gammas[h * S_ + i]));

  // ---------------- pass 1: softmax-1 stats (m1, den) ----------------
  float m1 = -INFINITY, den = 0.f;
  bf16x8 ka0, ka1, ka2, ka3;
  {
    const unsigned short* p0 = Kp + (size_t)li * DK_ + lg * 8;
    const unsigned short* p1 = Kp + (size_t)(16 + li) * DK_ + lg * 8;
    ka0 = *(const bf16x8*)p0; ka1 = *(const bf16x8*)(p0 + 32);
    ka2 = *(const bf16x8*)p1; ka3 = *(const bf16x8*)(p1 + 32);
  }
  for (int t = 0; t < ntile; ++t) {
    const int j0 = t * 32;
    const bool pf = (t + 1 < ntile);
    bf16x8 na0, na1, na2, na3;
    if (pf) {
      const unsigned short* p0 = Kp + (size_t)(j0 + 32 + li) * DK_ + lg * 8;
      const unsigned short* p1 = Kp + (size_t)(j0 + 48 + li) * DK_ + lg * 8;
      na0 = *(const bf16x8*)p0; na1 = *(const bf16x8*)(p0 + 32);
      na2 = *(const bf16x8*)p1; na3 = *(const bf16x8*)(p1 + 32);
    }
    f32x4 acc0 = {0.f,0.f,0.f,0.f}, acc1 = {0.f,0.f,0.f,0.f};
    acc0 = MFMA16(ka0, qb0, acc0); acc0 = MFMA16(ka1, qb1, acc0);
    acc1 = MFMA16(ka2, qb0, acc1); acc1 = MFMA16(ka3, qb1, acc1);
    // C: row = key j0 + (x<4?0:16) + lg*4 + (x&3), col = query li
    float sv[8]; float mloc = -INFINITY;
#pragma unroll
    for (int x = 0; x < 8; ++x) {
      float s = ((x < 4) ? acc0[x & 3] : acc1[x & 3]) * 0.125f;
      sv[x] = s;
      int j = j0 + ((x >> 2) << 4) + lg * 4 + (x & 3);
      mloc = fmaxf(mloc, (j <= i) ? s : -INFINITY);
    }
    mloc = fmaxf(mloc, __shfl_xor(mloc, 16, 64));
    mloc = fmaxf(mloc, __shfl_xor(mloc, 32, 64));
    float mn = fmaxf(m1, mloc);
    float sc = expf(m1 - mn);
    float ls = 0.f;
#pragma unroll
    for (int x = 0; x < 8; ++x) {
      int j = j0 + ((x >> 2) << 4) + lg * 4 + (x & 3);
      ls += (j <= i) ? expf(sv[x] - mn) : 0.f;
    }
    ls += __shfl_xor(ls, 16, 64);
    ls += __shfl_xor(ls, 32, 64);
    den = den * sc + ls;
    m1 = mn;
    if (pf) { ka0 = na0; ka1 = na1; ka2 = na2; ka3 = na3; }
  }
  const float inv1 = 1.f / den;

  // ---------------- pass 2: cumsum decay + online softmax-2 + PV ----------------
  float m2 = -INFINITY, l2 = 0.f, cum = 0.f;
  f32x4 o0 = {0.f,0.f,0.f,0.f}, o1 = {0.f,0.f,0.f,0.f};
  f32x4 o2 = {0.f,0.f,0.f,0.f}, o3 = {0.f,0.f,0.f,0.f};
  bf16x8 va0, va1, va2, va3;
  {
    const unsigned short* p0 = Kp + (size_t)li * DK_ + lg * 8;
    const unsigned short* p1 = Kp + (size_t)(16 + li) * DK_ + lg * 8;
    ka0 = *(const bf16x8*)p0; ka1 = *(const bf16x8*)(p0 + 32);
    ka2 = *(const bf16x8*)p1; ka3 = *(const bf16x8*)(p1 + 32);
    va0 = *(const bf16x8*)(Vp + (size_t)li * S_ + lg * 8);
    va1 = *(const bf16x8*)(Vp + (size_t)(16 + li) * S_ + lg * 8);
    va2 = *(const bf16x8*)(Vp + (size_t)(32 + li) * S_ + lg * 8);
    va3 = *(const bf16x8*)(Vp + (size_t)(48 + li) * S_ + lg * 8);
  }
  for (int t = 0; t < ntile; ++t) {
    const int j0 = t * 32;
    const bool pf = (t + 1 < ntile);
    bf16x8 na0, na1, na2, na3, nv0, nv1, nv2, nv3;
    if (pf) {
      const int j1 = j0 + 32;
      const unsigned short* p0 = Kp + (size_t)(j1 + li) * DK_ + lg * 8;
      const unsigned short* p1 = Kp + (size_t)(j1 + 16 + li) * DK_ + lg * 8;
      na0 = *(const bf16x8*)p0; na1 = *(const bf16x8*)(p0 + 32);
      na2 = *(const bf16x8*)p1; na3 = *(const bf16x8*)(p1 + 32);
      nv0 = *(const bf16x8*)(Vp + (size_t)li * S_ + j1 + lg * 8);
      nv1 = *(const bf16x8*)(Vp + (size_t)(16 + li) * S_ + j1 + lg * 8);
      nv2 = *(const bf16x8*)(Vp + (size_t)(32 + li) * S_ + j1 + lg * 8);
      nv3 = *(const bf16x8*)(Vp + (size_t)(48 + li) * S_ + j1 + lg * 8);
    }
    f32x4 acc0 = {0.f,0.f,0.f,0.f}, acc1 = {0.f,0.f,0.f,0.f};
    acc0 = MFMA16(ka0, qb0, acc0); acc0 = MFMA16(ka1, qb1, acc0);
    acc1 = MFMA16(ka2, qb0, acc1); acc1 = MFMA16(ka3, qb1, acc1);

    float sv[8], ev[8]; bool uv[8];
#pragma unroll
    for (int x = 0; x < 8; ++x) {
      float s = ((x < 4) ? acc0[x & 3] : acc1[x & 3]) * 0.125f;
      sv[x] = s;
      int j = j0 + ((x >> 2) << 4) + lg * 4 + (x & 3);
      uv[x] = (j <= i);
      ev[x] = uv[x] ? expf(s - m1) : 0.f;
    }
    // cross-lg inclusive scan of the two half-sums (key order: half0 lg*4.., half1 16+lg*4..)
    float L0 = ev[0] + ev[1] + ev[2] + ev[3];
    float L1 = ev[4] + ev[5] + ev[6] + ev[7];
    float v0 = L0;
    { float tt = __shfl_up(v0, 16, 64); if (lg >= 1) v0 += tt;
      tt = __shfl_up(v0, 32, 64); if (lg >= 2) v0 += tt; }
    float tot0 = __shfl(v0, li + 48, 64);
    float v1 = L1;
    { float tt = __shfl_up(v1, 16, 64); if (lg >= 1) v1 += tt;
      tt = __shfl_up(v1, 32, 64); if (lg >= 2) v1 += tt; }
    float tot1 = __shfl(v1, li + 48, 64);
    float base0 = cum + (v0 - L0);
    float base1 = cum + tot0 + (v1 - L1);
    cum += tot0 + tot1;

    float s2[8]; float run = base0;
#pragma unroll
    for (int x = 0; x < 8; ++x) {
      if (x == 4) run = base1;
      run += ev[x];
      int j = j0 + ((x >> 2) << 4) + lg * 4 + (x & 3);
      float rem = fmaxf(1.f - run * inv1, 0.f);
      float dist = sqrtf(fmaxf(rem * (float)(i - j), 0.f));
      float te = fminf(fmaxf(expf(dist * g), 1e-5f), 1e5f);
      s2[x] = uv[x] ? te * sv[x] : -INFINITY;
    }
    float mloc = s2[0];
#pragma unroll
    for (int x = 1; x < 8; ++x) mloc = fmaxf(mloc, s2[x]);
    mloc = fmaxf(mloc, __shfl_xor(mloc, 16, 64));
    mloc = fmaxf(mloc, __shfl_xor(mloc, 32, 64));
    float mn = fmaxf(m2, mloc);
    float f = expf(m2 - mn);
    float p[8]; float ls = 0.f;
#pragma unroll
    for (int x = 0; x < 8; ++x) { p[x] = expf(s2[x] - mn); ls += p[x]; }
    ls += __shfl_xor(ls, 16, 64);
    ls += __shfl_xor(ls, 32, 64);
    l2 = l2 * f + ls;
    m2 = mn;
    o0 *= f; o1 *= f; o2 *= f; o3 *= f;

    // P bounce: write [query li][key], read B-frag [li][lg*8..]
    { uint2 w0 = { pack2(p[0], p[1]), pack2(p[2], p[3]) };
      uint2 w1 = { pack2(p[4], p[5]), pack2(p[6], p[7]) };
      *(uint2*)&P[li][lg * 4] = w0;
      *(uint2*)&P[li][16 + lg * 4] = w1; }
    bf16x8 pb = *(const bf16x8*)&P[li][lg * 8];
    o0 = MFMA16(va0, pb, o0);
    o1 = MFMA16(va1, pb, o1);
    o2 = MFMA16(va2, pb, o2);
    o3 = MFMA16(va3, pb, o3);

    if (pf) { ka0 = na0; ka1 = na1; ka2 = na2; ka3 = na3;
              va0 = nv0; va1 = nv1; va2 = nv2; va3 = nv3; }
  }

  // epilogue: O^T fragments -> out_pre bf16; row 0 zeroed (shift_down)
  const float z = (i == 0) ? 0.f : (1.f / l2);
  unsigned short* dst = out_pre + ((size_t)(b * S_ + i)) * D_ + h * DK_;
  f32x4 oo[4] = { o0, o1, o2, o3 };
#pragma unroll
  for (int db = 0; db < 4; ++db) {
    ushort4 y = { f2bf(oo[db][0] * z), f2bf(oo[db][1] * z),
                  f2bf(oo[db][2] * z), f2bf(oo[db][3] * z) };
    *(ushort4*)&dst[db * 16 + lg * 4] = y;
  }
}

// ---------------------------------------------------------------------------
extern "C" void kernel_launch(void* const* d_in, const int* in_sizes, int n_in,
                              void* d_out, int out_size, void* d_ws, size_t ws_size,
                              hipStream_t stream) {
  const float* q  = (const float*)d_in[0];
  const float* k  = (const float*)d_in[1];
  const float* v  = (const float*)d_in[2];
  const float* Wq = (const float*)d_in[5];
  const float* bq = (const float*)d_in[6];
  const float* Wk = (const float*)d_in[7];
  const float* bk = (const float*)d_in[8];
  const float* Wv = (const float*)d_in[9];
  const float* bv = (const float*)d_in[10];
  const float* Wo = (const float*)d_in[11];
  const float* bo = (const float*)d_in[12];
  const float* gammas = (const float*)d_in[13];
  float* out = (float*)d_out;

  // ws: cs(512KB) | Abf 3x4MB | Wbf 4x512KB | Qbf 4MB | Kbf 4MB | Vtbf 4MB | out_pre 4MB  = ~30.5MB
  float* cs = (float*)d_ws;
  unsigned short* Abf  = (unsigned short*)(cs + (size_t)S_ * 32 * 2);
  unsigned short* Wbf  = Abf + (size_t)3 * 4096 * 512;
  unsigned short* Qbf  = Wbf + (size_t)4 * 512 * 512;
  unsigned short* Kbf  = Qbf + (size_t)B_ * H_ * S_ * DK_;
  unsigned short* Vtbf = Kbf + (size_t)B_ * H_ * S_ * DK_;
  unsigned short* out_pre = Vtbf + (size_t)B_ * H_ * S_ * DK_;

  rope_table_k<<<(S_ * 32 + 255) / 256, 256, 0, stream>>>(cs);
  cvt3_k<<<6144, 256, 0, stream>>>(q, k, v, Abf);
  cvt4_k<<<1024, 256, 0, stream>>>(Wq, Wk, Wv, Wo, Wbf);

  const size_t nA = (size_t)4096 * 512;
  const size_t nW = (size_t)512 * 512;
  dim3 gg(8, 64);
  gemm_bf<<<gg, 256, 0, stream>>>(Abf,          Wbf,          bq, Qbf,  cs, 1);
  gemm_bf<<<gg, 256, 0, stream>>>(Abf + nA,     Wbf + nW,     bk, Kbf,  cs, 1);
  gemm_bf<<<gg, 256, 0, stream>>>(Abf + 2 * nA, Wbf + 2 * nW, bv, Vtbf, cs, 2);

  attn2<<<dim3(128, B_ * H_), 64, 0, stream>>>(Qbf, Kbf, Vtbf, gammas, out_pre);

  gemm_bf<<<gg, 256, 0, stream>>>(out_pre, Wbf + 3 * nW, bo, out, cs, 0);
}

// Round 6
// 285.476 us; speedup vs baseline: 6.6754x; 1.5374x over previous
//
#include <hip/hip_runtime.h>
#include <math.h>

#define B_ 2
#define S_ 2048
#define D_ 512
#define H_ 8
#define DK_ 64

typedef __attribute__((ext_vector_type(8))) short bf16x8;
typedef __attribute__((ext_vector_type(4))) float f32x4;

#define MFMA16(A, Bv, C) __builtin_amdgcn_mfma_f32_16x16x32_bf16(A, Bv, C, 0, 0, 0)

__device__ inline unsigned short f2bf(float x) {
  unsigned u = __float_as_uint(x);
  unsigned r = (u + 0x7fffu + ((u >> 16) & 1u)) >> 16;
  return (unsigned short)r;
}
__device__ inline unsigned pack2(float a, float b) {
  return (unsigned)f2bf(a) | ((unsigned)f2bf(b) << 16);
}

// ---------------------------------------------------------------------------
// RoPE cos/sin table
// ---------------------------------------------------------------------------
__global__ void rope_table_k(float* cs) {
  int idx = blockIdx.x * blockDim.x + threadIdx.x;
  if (idx >= S_ * 32) return;
  int s = idx >> 5, i = idx & 31;
  float invf = powf(10000.0f, -(float)(2 * i) / 64.0f);
  float ang = (float)s * invf;
  double a = (double)ang;
  cs[idx * 2]     = (float)cos(a);
  cs[idx * 2 + 1] = (float)sin(a);
}

// ---------------------------------------------------------------------------
// f32 -> bf16 converters
// ---------------------------------------------------------------------------
__global__ __launch_bounds__(256)
void cvt3_k(const float* __restrict__ a, const float* __restrict__ b,
            const float* __restrict__ c, unsigned short* __restrict__ dst) {
  size_t idx = ((size_t)blockIdx.x * 256 + threadIdx.x) * 4;
  const size_t per = (size_t)4096 * 512;
  const float* src; size_t r;
  if (idx < per)            { src = a; r = idx; }
  else if (idx < 2 * per)   { src = b; r = idx - per; }
  else                      { src = c; r = idx - 2 * per; }
  float4 x = *(const float4*)(src + r);
  ushort4 y = { f2bf(x.x), f2bf(x.y), f2bf(x.z), f2bf(x.w) };
  *(ushort4*)(dst + idx) = y;
}
__global__ __launch_bounds__(256)
void cvt4_k(const float* __restrict__ a, const float* __restrict__ b,
            const float* __restrict__ c, const float* __restrict__ d,
            unsigned short* __restrict__ dst) {
  size_t idx = ((size_t)blockIdx.x * 256 + threadIdx.x) * 4;
  const size_t per = (size_t)512 * 512;
  const float* src; size_t r;
  if (idx < per)            { src = a; r = idx; }
  else if (idx < 2 * per)   { src = b; r = idx - per; }
  else if (idx < 3 * per)   { src = c; r = idx - 2 * per; }
  else                      { src = d; r = idx - 3 * per; }
  float4 x = *(const float4*)(src + r);
  ushort4 y = { f2bf(x.x), f2bf(x.y), f2bf(x.z), f2bf(x.w) };
  *(ushort4*)(dst + idx) = y;
}

// ---------------------------------------------------------------------------
// bf16 MFMA GEMM (unchanged from round 5)
// ---------------------------------------------------------------------------
__global__ __launch_bounds__(256)
void gemm_bf(const unsigned short* __restrict__ A,
             const unsigned short* __restrict__ W,
             const float* __restrict__ bias, void* __restrict__ Cout,
             const float* __restrict__ cs, int mode) {
  const int bm = blockIdx.y * 64, bn = blockIdx.x * 64;
  const int tid = threadIdx.x, w = tid >> 6, lane = tid & 63;
  const int li = lane & 15, lg = lane >> 4;
  __shared__ __align__(16) unsigned short As[64 * 64];
  __shared__ __align__(16) unsigned short Ws[64 * 64];
  f32x4 acc[4] = {{0.f,0.f,0.f,0.f},{0.f,0.f,0.f,0.f},{0.f,0.f,0.f,0.f},{0.f,0.f,0.f,0.f}};

  const int Bo0 = tid * 16, Bo1 = tid * 16 + 4096;
  const int r0 = Bo0 >> 7, c0 = Bo0 & 127;
  const int r1 = Bo1 >> 7, c1 = Bo1 & 127;
  const int so0 = (r0 * 128 + (c0 ^ ((r0 & 7) << 4))) >> 1;
  const int so1 = (r1 * 128 + (c1 ^ ((r1 & 7) << 4))) >> 1;

  const char* Abase = (const char*)A;
  const char* Wbase = (const char*)W;
  uint4 ra0 = *(const uint4*)(Abase + (size_t)(bm + r0) * 1024 + c0);
  uint4 ra1 = *(const uint4*)(Abase + (size_t)(bm + r1) * 1024 + c1);
  uint4 rw0 = *(const uint4*)(Wbase + (size_t)(bn + r0) * 1024 + c0);
  uint4 rw1 = *(const uint4*)(Wbase + (size_t)(bn + r1) * 1024 + c1);

  for (int t = 0; t < 8; ++t) {
    __syncthreads();
    *(uint4*)&As[so0] = ra0; *(uint4*)&As[so1] = ra1;
    *(uint4*)&Ws[so0] = rw0; *(uint4*)&Ws[so1] = rw1;
    __syncthreads();
    if (t < 7) {
      int k0 = (t + 1) * 128;
      ra0 = *(const uint4*)(Abase + (size_t)(bm + r0) * 1024 + k0 + c0);
      ra1 = *(const uint4*)(Abase + (size_t)(bm + r1) * 1024 + k0 + c1);
      rw0 = *(const uint4*)(Wbase + (size_t)(bn + r0) * 1024 + k0 + c0);
      rw1 = *(const uint4*)(Wbase + (size_t)(bn + r1) * 1024 + k0 + c1);
    }
#pragma unroll
    for (int kk = 0; kk < 2; ++kk) {
      const int brow = w * 16 + li;
      bf16x8 bf = *(const bf16x8*)&Ws[brow * 64 + (((kk * 64 + lg * 16) ^ ((brow & 7) << 4)) >> 1)];
#pragma unroll
      for (int mt = 0; mt < 4; ++mt) {
        const int arow = mt * 16 + li;
        bf16x8 af = *(const bf16x8*)&As[arow * 64 + (((kk * 64 + lg * 16) ^ ((arow & 7) << 4)) >> 1)];
        acc[mt] = MFMA16(af, bf, acc[mt]);
      }
    }
  }

  const int n = bn + w * 16 + li;
  const float bv = bias[n];
  if (mode == 0) {
    float* C = (float*)Cout;
#pragma unroll
    for (int mt = 0; mt < 4; ++mt)
#pragma unroll
      for (int r = 0; r < 4; ++r) {
        int m = bm + mt * 16 + lg * 4 + r;
        C[(size_t)m * 512 + n] = acc[mt][r] + bv;
      }
  } else if (mode == 1) {
    unsigned short* C = (unsigned short*)Cout;
    const int d = n & 63, hh = n >> 6, p = d >> 1;
#pragma unroll
    for (int mt = 0; mt < 4; ++mt)
#pragma unroll
      for (int r = 0; r < 4; ++r) {
        int m = bm + mt * 16 + lg * 4 + r;
        int bb = m >> 11, sp = m & (S_ - 1);
        float val = acc[mt][r] + bv;
        float other = __shfl_xor(val, 1, 64);
        const float* cp = cs + ((size_t)sp * 32 + p) * 2;
        float cc = cp[0], sn = cp[1];
        float y = (d & 1) ? (val * cc + other * sn) : (val * cc - other * sn);
        C[(((size_t)bb * H_ + hh) * S_ + sp) * DK_ + d] = f2bf(y);
      }
  } else {
    unsigned short* C = (unsigned short*)Cout;
    const int d = n & 63, hh = n >> 6;
#pragma unroll
    for (int mt = 0; mt < 4; ++mt) {
      int m0 = bm + mt * 16 + lg * 4;
      int bb = m0 >> 11, sp0 = m0 & (S_ - 1);
      ushort4 y = { f2bf(acc[mt][0] + bv), f2bf(acc[mt][1] + bv),
                    f2bf(acc[mt][2] + bv), f2bf(acc[mt][3] + bv) };
      *(ushort4*)&C[(((size_t)bb * H_ + hh) * DK_ + d) * S_ + sp0] = y;
    }
  }
}

// ---------------------------------------------------------------------------
// Split-K attention: block = (bh, 16 queries) x 4 waves; wave w owns a
// contiguous quarter of the key tiles. Cumsum prefix comes from pass-1
// partial sums, so split-K is exact.
// ---------------------------------------------------------------------------
__global__ __launch_bounds__(256)
void attn3(const unsigned short* __restrict__ Qbf,
           const unsigned short* __restrict__ Kbf,
           const unsigned short* __restrict__ Vtbf,
           const float* __restrict__ gammas,
           unsigned short* __restrict__ out_pre) {
  const int qt = 127 - (int)blockIdx.x;     // big blocks first
  const int bh = blockIdx.y;
  const int h = bh & (H_ - 1), b = bh >> 3;
  const int i0 = qt * 16;
  const int tid = threadIdx.x;
  const int w = tid >> 6, lane = tid & 63;
  const int li = lane & 15, lg = lane >> 4;
  const int i = i0 + li;                    // this lane's query row

  __shared__ __align__(16) unsigned short P[4][16][40];
  __shared__ float sm1[4][16], sden[4][16], sm2[4][16], sl2[4][16];
  __shared__ float Obuf[4][64][17];         // padded: lane stride 17 floats

  const unsigned short* Qp = Qbf + (size_t)bh * (S_ * DK_);
  const unsigned short* Kp = Kbf + (size_t)bh * (S_ * DK_);
  const unsigned short* Vp = Vtbf + (size_t)bh * (DK_ * S_);

  bf16x8 qb0 = *(const bf16x8*)(Qp + (size_t)i * DK_ + lg * 8);
  bf16x8 qb1 = *(const bf16x8*)(Qp + (size_t)i * DK_ + 32 + lg * 8);

  const int ntile = (i0 >> 5) + 1;
  const int nt4 = (ntile + 3) >> 2;
  const int tb = (w * nt4 < ntile) ? w * nt4 : ntile;
  const int te = (tb + nt4 < ntile) ? tb + nt4 : ntile;

  const float g = -log1pf(__expf(gammas[h * S_ + i]));

  // ---------------- pass 1: chunk-local softmax-1 stats ----------------
  float m1w = -INFINITY, denw = 0.f;
  bf16x8 ka0, ka1, ka2, ka3;
  if (tb < te) {
    const int jb = tb * 32;
    const unsigned short* p0 = Kp + (size_t)(jb + li) * DK_ + lg * 8;
    const unsigned short* p1 = Kp + (size_t)(jb + 16 + li) * DK_ + lg * 8;
    ka0 = *(const bf16x8*)p0; ka1 = *(const bf16x8*)(p0 + 32);
    ka2 = *(const bf16x8*)p1; ka3 = *(const bf16x8*)(p1 + 32);
  }
  for (int t = tb; t < te; ++t) {
    const int j0 = t * 32;
    const bool pf = (t + 1 < te);
    bf16x8 na0, na1, na2, na3;
    if (pf) {
      const unsigned short* p0 = Kp + (size_t)(j0 + 32 + li) * DK_ + lg * 8;
      const unsigned short* p1 = Kp + (size_t)(j0 + 48 + li) * DK_ + lg * 8;
      na0 = *(const bf16x8*)p0; na1 = *(const bf16x8*)(p0 + 32);
      na2 = *(const bf16x8*)p1; na3 = *(const bf16x8*)(p1 + 32);
    }
    f32x4 acc0 = {0.f,0.f,0.f,0.f}, acc1 = {0.f,0.f,0.f,0.f};
    acc0 = MFMA16(ka0, qb0, acc0); acc0 = MFMA16(ka1, qb1, acc0);
    acc1 = MFMA16(ka2, qb0, acc1); acc1 = MFMA16(ka3, qb1, acc1);
    float sv[8]; float mloc = -INFINITY;
#pragma unroll
    for (int x = 0; x < 8; ++x) {
      float s = ((x < 4) ? acc0[x & 3] : acc1[x & 3]) * 0.125f;
      sv[x] = s;
      int j = j0 + ((x >> 2) << 4) + lg * 4 + (x & 3);
      mloc = fmaxf(mloc, (j <= i) ? s : -INFINITY);
    }
    mloc = fmaxf(mloc, __shfl_xor(mloc, 16, 64));
    mloc = fmaxf(mloc, __shfl_xor(mloc, 32, 64));
    float mn = fmaxf(m1w, mloc);
    float sc = __expf(m1w - mn);
    float ls = 0.f;
#pragma unroll
    for (int x = 0; x < 8; ++x) {
      int j = j0 + ((x >> 2) << 4) + lg * 4 + (x & 3);
      ls += (j <= i) ? __expf(sv[x] - mn) : 0.f;
    }
    ls += __shfl_xor(ls, 16, 64);
    ls += __shfl_xor(ls, 32, 64);
    denw = denw * sc + ls;
    m1w = mn;
    if (pf) { ka0 = na0; ka1 = na1; ka2 = na2; ka3 = na3; }
  }
  if (lg == 0) { sm1[w][li] = m1w; sden[w][li] = denw; }
  __syncthreads();

  // global softmax-1 stats + this wave's cumsum prefix
  const float gm0 = sm1[0][li], gm1v = sm1[1][li], gm2v = sm1[2][li], gm3v = sm1[3][li];
  const float m1 = fmaxf(fmaxf(gm0, gm1v), fmaxf(gm2v, gm3v));   // finite (key 0 unmasked)
  const float d0 = sden[0][li] * __expf(gm0 - m1);
  const float d1 = sden[1][li] * __expf(gm1v - m1);
  const float d2 = sden[2][li] * __expf(gm2v - m1);
  const float d3 = sden[3][li] * __expf(gm3v - m1);
  const float den = d0 + d1 + d2 + d3;
  const float inv1 = 1.f / den;
  float cum = 0.f;
  if (w > 0) cum += d0;
  if (w > 1) cum += d1;
  if (w > 2) cum += d2;

  // ---------------- pass 2: decay + online softmax-2 + PV (chunk) ----------------
  float m2w = -INFINITY, l2w = 0.f;
  f32x4 o0 = {0.f,0.f,0.f,0.f}, o1 = {0.f,0.f,0.f,0.f};
  f32x4 o2 = {0.f,0.f,0.f,0.f}, o3 = {0.f,0.f,0.f,0.f};
  bf16x8 va0, va1, va2, va3;
  if (tb < te) {
    const int jb = tb * 32;
    const unsigned short* p0 = Kp + (size_t)(jb + li) * DK_ + lg * 8;
    const unsigned short* p1 = Kp + (size_t)(jb + 16 + li) * DK_ + lg * 8;
    ka0 = *(const bf16x8*)p0; ka1 = *(const bf16x8*)(p0 + 32);
    ka2 = *(const bf16x8*)p1; ka3 = *(const bf16x8*)(p1 + 32);
    va0 = *(const bf16x8*)(Vp + (size_t)li * S_ + jb + lg * 8);
    va1 = *(const bf16x8*)(Vp + (size_t)(16 + li) * S_ + jb + lg * 8);
    va2 = *(const bf16x8*)(Vp + (size_t)(32 + li) * S_ + jb + lg * 8);
    va3 = *(const bf16x8*)(Vp + (size_t)(48 + li) * S_ + jb + lg * 8);
  }
  for (int t = tb; t < te; ++t) {
    const int j0 = t * 32;
    const bool pf = (t + 1 < te);
    bf16x8 na0, na1, na2, na3, nv0, nv1, nv2, nv3;
    if (pf) {
      const int j1 = j0 + 32;
      const unsigned short* p0 = Kp + (size_t)(j1 + li) * DK_ + lg * 8;
      const unsigned short* p1 = Kp + (size_t)(j1 + 16 + li) * DK_ + lg * 8;
      na0 = *(const bf16x8*)p0; na1 = *(const bf16x8*)(p0 + 32);
      na2 = *(const bf16x8*)p1; na3 = *(const bf16x8*)(p1 + 32);
      nv0 = *(const bf16x8*)(Vp + (size_t)li * S_ + j1 + lg * 8);
      nv1 = *(const bf16x8*)(Vp + (size_t)(16 + li) * S_ + j1 + lg * 8);
      nv2 = *(const bf16x8*)(Vp + (size_t)(32 + li) * S_ + j1 + lg * 8);
      nv3 = *(const bf16x8*)(Vp + (size_t)(48 + li) * S_ + j1 + lg * 8);
    }
    f32x4 acc0 = {0.f,0.f,0.f,0.f}, acc1 = {0.f,0.f,0.f,0.f};
    acc0 = MFMA16(ka0, qb0, acc0); acc0 = MFMA16(ka1, qb1, acc0);
    acc1 = MFMA16(ka2, qb0, acc1); acc1 = MFMA16(ka3, qb1, acc1);

    float sv[8], ev[8]; bool uv[8];
#pragma unroll
    for (int x = 0; x < 8; ++x) {
      float s = ((x < 4) ? acc0[x & 3] : acc1[x & 3]) * 0.125f;
      sv[x] = s;
      int j = j0 + ((x >> 2) << 4) + lg * 4 + (x & 3);
      uv[x] = (j <= i);
      ev[x] = uv[x] ? __expf(s - m1) : 0.f;
    }
    float L0 = ev[0] + ev[1] + ev[2] + ev[3];
    float L1 = ev[4] + ev[5] + ev[6] + ev[7];
    float v0 = L0;
    { float tt = __shfl_up(v0, 16, 64); if (lg >= 1) v0 += tt;
      tt = __shfl_up(v0, 32, 64); if (lg >= 2) v0 += tt; }
    float tot0 = __shfl(v0, li + 48, 64);
    float v1 = L1;
    { float tt = __shfl_up(v1, 16, 64); if (lg >= 1) v1 += tt;
      tt = __shfl_up(v1, 32, 64); if (lg >= 2) v1 += tt; }
    float tot1 = __shfl(v1, li + 48, 64);
    float base0 = cum + (v0 - L0);
    float base1 = cum + tot0 + (v1 - L1);
    cum += tot0 + tot1;

    float s2[8]; float run = base0;
#pragma unroll
    for (int x = 0; x < 8; ++x) {
      if (x == 4) run = base1;
      run += ev[x];
      int j = j0 + ((x >> 2) << 4) + lg * 4 + (x & 3);
      float rem = fmaxf(1.f - run * inv1, 0.f);
      float dist = sqrtf(fmaxf(rem * (float)(i - j), 0.f));
      float te2 = fminf(fmaxf(__expf(dist * g), 1e-5f), 1e5f);
      s2[x] = uv[x] ? te2 * sv[x] : -INFINITY;
    }
    float mloc = s2[0];
#pragma unroll
    for (int x = 1; x < 8; ++x) mloc = fmaxf(mloc, s2[x]);
    mloc = fmaxf(mloc, __shfl_xor(mloc, 16, 64));
    mloc = fmaxf(mloc, __shfl_xor(mloc, 32, 64));
    float mn = fmaxf(m2w, mloc);
    float f = __expf(m2w - mn);
    float p[8]; float ls = 0.f;
#pragma unroll
    for (int x = 0; x < 8; ++x) { p[x] = __expf(s2[x] - mn); ls += p[x]; }
    ls += __shfl_xor(ls, 16, 64);
    ls += __shfl_xor(ls, 32, 64);
    l2w = l2w * f + ls;
    m2w = mn;
    o0 *= f; o1 *= f; o2 *= f; o3 *= f;

    { uint2 w0v = { pack2(p[0], p[1]), pack2(p[2], p[3]) };
      uint2 w1v = { pack2(p[4], p[5]), pack2(p[6], p[7]) };
      *(uint2*)&P[w][li][lg * 4] = w0v;
      *(uint2*)&P[w][li][16 + lg * 4] = w1v; }
    bf16x8 pb = *(const bf16x8*)&P[w][li][lg * 8];
    o0 = MFMA16(va0, pb, o0);
    o1 = MFMA16(va1, pb, o1);
    o2 = MFMA16(va2, pb, o2);
    o3 = MFMA16(va3, pb, o3);

    if (pf) { ka0 = na0; ka1 = na1; ka2 = na2; ka3 = na3;
              va0 = nv0; va1 = nv1; va2 = nv2; va3 = nv3; }
  }

  // ---------------- merge 4 chunk partials ----------------
  if (lg == 0) { sm2[w][li] = m2w; sl2[w][li] = l2w; }
  {
    f32x4 oo[4] = { o0, o1, o2, o3 };
#pragma unroll
    for (int db = 0; db < 4; ++db)
#pragma unroll
      for (int e = 0; e < 4; ++e)
        Obuf[w][lane][db * 4 + e] = oo[db][e];
  }
  __syncthreads();
  if (w == 0) {
    const float q0 = sm2[0][li], q1 = sm2[1][li], q2 = sm2[2][li], q3 = sm2[3][li];
    const float m2 = fmaxf(fmaxf(q0, q1), fmaxf(q2, q3));   // finite (wave 0 nonempty)
    const float f0 = __expf(q0 - m2), f1 = __expf(q1 - m2);
    const float f2 = __expf(q2 - m2), f3 = __expf(q3 - m2);
    const float l2 = sl2[0][li] * f0 + sl2[1][li] * f1 + sl2[2][li] * f2 + sl2[3][li] * f3;
    const float z = (i == 0) ? 0.f : (1.f / l2);
    unsigned short* dst = out_pre + ((size_t)(b * S_ + i)) * D_ + h * DK_;
#pragma unroll
    for (int db = 0; db < 4; ++db) {
      float vo[4];
#pragma unroll
      for (int e = 0; e < 4; ++e)
        vo[e] = (Obuf[0][lane][db * 4 + e] * f0 + Obuf[1][lane][db * 4 + e] * f1 +
                 Obuf[2][lane][db * 4 + e] * f2 + Obuf[3][lane][db * 4 + e] * f3) * z;
      ushort4 y = { f2bf(vo[0]), f2bf(vo[1]), f2bf(vo[2]), f2bf(vo[3]) };
      *(ushort4*)&dst[db * 16 + lg * 4] = y;
    }
  }
}

// ---------------------------------------------------------------------------
extern "C" void kernel_launch(void* const* d_in, const int* in_sizes, int n_in,
                              void* d_out, int out_size, void* d_ws, size_t ws_size,
                              hipStream_t stream) {
  const float* q  = (const float*)d_in[0];
  const float* k  = (const float*)d_in[1];
  const float* v  = (const float*)d_in[2];
  const float* Wq = (const float*)d_in[5];
  const float* bq = (const float*)d_in[6];
  const float* Wk = (const float*)d_in[7];
  const float* bk = (const float*)d_in[8];
  const float* Wv = (const float*)d_in[9];
  const float* bv = (const float*)d_in[10];
  const float* Wo = (const float*)d_in[11];
  const float* bo = (const float*)d_in[12];
  const float* gammas = (const float*)d_in[13];
  float* out = (float*)d_out;

  float* cs = (float*)d_ws;
  unsigned short* Abf  = (unsigned short*)(cs + (size_t)S_ * 32 * 2);
  unsigned short* Wbf  = Abf + (size_t)3 * 4096 * 512;
  unsigned short* Qbf  = Wbf + (size_t)4 * 512 * 512;
  unsigned short* Kbf  = Qbf + (size_t)B_ * H_ * S_ * DK_;
  unsigned short* Vtbf = Kbf + (size_t)B_ * H_ * S_ * DK_;
  unsigned short* out_pre = Vtbf + (size_t)B_ * H_ * S_ * DK_;

  rope_table_k<<<(S_ * 32 + 255) / 256, 256, 0, stream>>>(cs);
  cvt3_k<<<6144, 256, 0, stream>>>(q, k, v, Abf);
  cvt4_k<<<1024, 256, 0, stream>>>(Wq, Wk, Wv, Wo, Wbf);

  const size_t nA = (size_t)4096 * 512;
  const size_t nW = (size_t)512 * 512;
  dim3 gg(8, 64);
  gemm_bf<<<gg, 256, 0, stream>>>(Abf,          Wbf,          bq, Qbf,  cs, 1);
  gemm_bf<<<gg, 256, 0, stream>>>(Abf + nA,     Wbf + nW,     bk, Kbf,  cs, 1);
  gemm_bf<<<gg, 256, 0, stream>>>(Abf + 2 * nA, Wbf + 2 * nW, bv, Vtbf, cs, 2);

  attn3<<<dim3(128, B_ * H_), 256, 0, stream>>>(Qbf, Kbf, Vtbf, gammas, out_pre);

  gemm_bf<<<gg, 256, 0, stream>>>(out_pre, Wbf + 3 * nW, bo, out, cs, 0);
}

// Round 7
// 270.795 us; speedup vs baseline: 7.0373x; 1.0542x over previous
//
#include <hip/hip_runtime.h>
#include <math.h>

#define B_ 2
#define S_ 2048
#define D_ 512
#define H_ 8
#define DK_ 64

typedef __attribute__((ext_vector_type(8))) short bf16x8;
typedef __attribute__((ext_vector_type(4))) float f32x4;

#define MFMA16(A, Bv, C) __builtin_amdgcn_mfma_f32_16x16x32_bf16(A, Bv, C, 0, 0, 0)

__device__ inline unsigned short f2bf(float x) {
  unsigned u = __float_as_uint(x);
  unsigned r = (u + 0x7fffu + ((u >> 16) & 1u)) >> 16;
  return (unsigned short)r;
}
__device__ inline unsigned pack2(float a, float b) {
  return (unsigned)f2bf(a) | ((unsigned)f2bf(b) << 16);
}
__device__ __forceinline__ void gload16(const void* g, void* l) {
  __builtin_amdgcn_global_load_lds((const __attribute__((address_space(1))) unsigned*)g,
                                   (__attribute__((address_space(3))) unsigned*)l, 16, 0, 0);
}

// ---------------------------------------------------------------------------
// RoPE cos/sin table
// ---------------------------------------------------------------------------
__global__ void rope_table_k(float* cs) {
  int idx = blockIdx.x * blockDim.x + threadIdx.x;
  if (idx >= S_ * 32) return;
  int s = idx >> 5, i = idx & 31;
  float invf = powf(10000.0f, -(float)(2 * i) / 64.0f);
  float ang = (float)s * invf;
  double a = (double)ang;
  cs[idx * 2]     = (float)cos(a);
  cs[idx * 2 + 1] = (float)sin(a);
}

// ---------------------------------------------------------------------------
// f32 -> bf16 converters
// ---------------------------------------------------------------------------
__global__ __launch_bounds__(256)
void cvt3_k(const float* __restrict__ a, const float* __restrict__ b,
            const float* __restrict__ c, unsigned short* __restrict__ dst) {
  size_t idx = ((size_t)blockIdx.x * 256 + threadIdx.x) * 4;
  const size_t per = (size_t)4096 * 512;
  const float* src; size_t r;
  if (idx < per)            { src = a; r = idx; }
  else if (idx < 2 * per)   { src = b; r = idx - per; }
  else                      { src = c; r = idx - 2 * per; }
  float4 x = *(const float4*)(src + r);
  ushort4 y = { f2bf(x.x), f2bf(x.y), f2bf(x.z), f2bf(x.w) };
  *(ushort4*)(dst + idx) = y;
}
__global__ __launch_bounds__(256)
void cvt4_k(const float* __restrict__ a, const float* __restrict__ b,
            const float* __restrict__ c, const float* __restrict__ d,
            unsigned short* __restrict__ dst) {
  size_t idx = ((size_t)blockIdx.x * 256 + threadIdx.x) * 4;
  const size_t per = (size_t)512 * 512;
  const float* src; size_t r;
  if (idx < per)            { src = a; r = idx; }
  else if (idx < 2 * per)   { src = b; r = idx - per; }
  else if (idx < 3 * per)   { src = c; r = idx - 2 * per; }
  else                      { src = d; r = idx - 3 * per; }
  float4 x = *(const float4*)(src + r);
  ushort4 y = { f2bf(x.x), f2bf(x.y), f2bf(x.z), f2bf(x.w) };
  *(ushort4*)(dst + idx) = y;
}

// ---------------------------------------------------------------------------
// m97-pattern bf16 GEMM: C = A(Mx512) * W(512x512)^T + bias
// tile 128x64, BK=64, 4 waves (2x2), double-buffered LDS, global_load_lds.
// Swizzle: LDS[r][c16] = global[r][c16 ^ (r&7)] (16B chunks), read with same XOR.
// mode 0: f32 out; mode 1: RoPE+bf16 -> (B,H,S,DK); mode 2: bf16 -> (B,H,DK,S)
// ---------------------------------------------------------------------------
__global__ __launch_bounds__(256)
void gemm2(const unsigned short* __restrict__ A,
           const unsigned short* __restrict__ W,
           const float* __restrict__ bias, void* __restrict__ Cout,
           const float* __restrict__ cs, int mode) {
  const int bm = blockIdx.y * 128, bn = blockIdx.x * 64;
  const int tid = threadIdx.x, w = tid >> 6, lane = tid & 63;
  const int li = lane & 15, lg = lane >> 4;
  const int wr = w >> 1, wc = w & 1;

  __shared__ __align__(16) unsigned short As[2][128 * 64];
  __shared__ __align__(16) unsigned short Ws[2][64 * 64];

  f32x4 acc[4][2] = {};

  const char* Abase = (const char*)A;
  const char* Wbase = (const char*)W;
  const int lr = lane >> 3;                 // lane's row within 8-row slab
  const int lc = (lane & 7) ^ lr;           // inverse-swizzled source chunk

  // stage K-slab t into buffer buf (wave-cooperative, 6 x gload16 per lane)
  auto stage = [&](int buf, int t) {
    const char* Ab = Abase + (size_t)bm * 1024 + t * 128;
    const char* Wb = Wbase + (size_t)bn * 1024 + t * 128;
    char* AsB = (char*)&As[buf][0];
    char* WsB = (char*)&Ws[buf][0];
#pragma unroll
    for (int it = 0; it < 4; ++it) {
      int R0 = (w * 4 + it) * 8;
      gload16(Ab + (size_t)(R0 + lr) * 1024 + lc * 16, AsB + R0 * 128);
    }
#pragma unroll
    for (int it = 0; it < 2; ++it) {
      int R0 = (w * 2 + it) * 8;
      gload16(Wb + (size_t)(R0 + lr) * 1024 + lc * 16, WsB + R0 * 128);
    }
  };

  stage(0, 0);
  int cur = 0;
  for (int t = 0; t < 8; ++t) {
    __syncthreads();                        // drains gload queue (vmcnt 0) + sync
    if (t < 7) stage(cur ^ 1, t + 1);
#pragma unroll
    for (int kk = 0; kk < 2; ++kk) {
      const int chunk = lg + kk * 4;
      bf16x8 bfr[2];
#pragma unroll
      for (int nt = 0; nt < 2; ++nt) {
        int row = wc * 32 + nt * 16 + li;
        bfr[nt] = *(const bf16x8*)&Ws[cur][row * 64 + ((chunk ^ (row & 7)) << 3)];
      }
#pragma unroll
      for (int mt = 0; mt < 4; ++mt) {
        int row = wr * 64 + mt * 16 + li;
        bf16x8 af = *(const bf16x8*)&As[cur][row * 64 + ((chunk ^ (row & 7)) << 3)];
        acc[mt][0] = MFMA16(af, bfr[0], acc[mt][0]);
        acc[mt][1] = MFMA16(af, bfr[1], acc[mt][1]);
      }
    }
    cur ^= 1;
  }

#pragma unroll
  for (int nt = 0; nt < 2; ++nt) {
    const int n = bn + wc * 32 + nt * 16 + li;
    const float bv = bias[n];
    if (mode == 0) {
      float* C = (float*)Cout;
#pragma unroll
      for (int mt = 0; mt < 4; ++mt)
#pragma unroll
        for (int r = 0; r < 4; ++r) {
          int m = bm + wr * 64 + mt * 16 + lg * 4 + r;
          C[(size_t)m * 512 + n] = acc[mt][nt][r] + bv;
        }
    } else if (mode == 1) {
      unsigned short* C = (unsigned short*)Cout;
      const int d = n & 63, hh = n >> 6, p = d >> 1;
#pragma unroll
      for (int mt = 0; mt < 4; ++mt)
#pragma unroll
        for (int r = 0; r < 4; ++r) {
          int m = bm + wr * 64 + mt * 16 + lg * 4 + r;
          int bb = m >> 11, sp = m & (S_ - 1);
          float val = acc[mt][nt][r] + bv;
          float other = __shfl_xor(val, 1, 64);
          const float* cp = cs + ((size_t)sp * 32 + p) * 2;
          float cc = cp[0], sn = cp[1];
          float y = (d & 1) ? (val * cc + other * sn) : (val * cc - other * sn);
          C[(((size_t)bb * H_ + hh) * S_ + sp) * DK_ + d] = f2bf(y);
        }
    } else {
      unsigned short* C = (unsigned short*)Cout;
      const int d = n & 63, hh = n >> 6;
#pragma unroll
      for (int mt = 0; mt < 4; ++mt) {
        int m0 = bm + wr * 64 + mt * 16 + lg * 4;
        int bb = m0 >> 11, sp0 = m0 & (S_ - 1);
        ushort4 y = { f2bf(acc[mt][nt][0] + bv), f2bf(acc[mt][nt][1] + bv),
                      f2bf(acc[mt][nt][2] + bv), f2bf(acc[mt][nt][3] + bv) };
        *(ushort4*)&C[(((size_t)bb * H_ + hh) * DK_ + d) * S_ + sp0] = y;
      }
    }
  }
}

// ---------------------------------------------------------------------------
// Split-K attention, work-balanced: block handles query tiles (127-bx) and bx
// sequentially -> every block does ~65 key-tiles. 4 waves split keys.
// ---------------------------------------------------------------------------
__global__ __launch_bounds__(256)
void attn3(const unsigned short* __restrict__ Qbf,
           const unsigned short* __restrict__ Kbf,
           const unsigned short* __restrict__ Vtbf,
           const float* __restrict__ gammas,
           unsigned short* __restrict__ out_pre) {
  const int bx = (int)blockIdx.x;           // 0..63
  const int bh = blockIdx.y;
  const int h = bh & (H_ - 1), b = bh >> 3;
  const int tid = threadIdx.x;
  const int w = tid >> 6, lane = tid & 63;
  const int li = lane & 15, lg = lane >> 4;

  __shared__ __align__(16) unsigned short P[4][16][40];
  __shared__ float sm1[4][16], sden[4][16], sm2[4][16], sl2[4][16];
  __shared__ float Obuf[4][64][17];

  const unsigned short* Qp = Qbf + (size_t)bh * (S_ * DK_);
  const unsigned short* Kp = Kbf + (size_t)bh * (S_ * DK_);
  const unsigned short* Vp = Vtbf + (size_t)bh * (DK_ * S_);

  for (int half = 0; half < 2; ++half) {
    const int qt = half ? bx : (127 - bx);
    const int i0 = qt * 16;
    const int i = i0 + li;

    bf16x8 qb0 = *(const bf16x8*)(Qp + (size_t)i * DK_ + lg * 8);
    bf16x8 qb1 = *(const bf16x8*)(Qp + (size_t)i * DK_ + 32 + lg * 8);

    const int ntile = (i0 >> 5) + 1;
    const int nt4 = (ntile + 3) >> 2;
    const int tb = (w * nt4 < ntile) ? w * nt4 : ntile;
    const int te = (tb + nt4 < ntile) ? tb + nt4 : ntile;

    const float g = -log1pf(__expf(gammas[h * S_ + i]));

    // ---------------- pass 1: chunk-local softmax-1 stats ----------------
    float m1w = -INFINITY, denw = 0.f;
    bf16x8 ka0, ka1, ka2, ka3;
    if (tb < te) {
      const int jb = tb * 32;
      const unsigned short* p0 = Kp + (size_t)(jb + li) * DK_ + lg * 8;
      const unsigned short* p1 = Kp + (size_t)(jb + 16 + li) * DK_ + lg * 8;
      ka0 = *(const bf16x8*)p0; ka1 = *(const bf16x8*)(p0 + 32);
      ka2 = *(const bf16x8*)p1; ka3 = *(const bf16x8*)(p1 + 32);
    }
    for (int t = tb; t < te; ++t) {
      const int j0 = t * 32;
      const bool pf = (t + 1 < te);
      bf16x8 na0, na1, na2, na3;
      if (pf) {
        const unsigned short* p0 = Kp + (size_t)(j0 + 32 + li) * DK_ + lg * 8;
        const unsigned short* p1 = Kp + (size_t)(j0 + 48 + li) * DK_ + lg * 8;
        na0 = *(const bf16x8*)p0; na1 = *(const bf16x8*)(p0 + 32);
        na2 = *(const bf16x8*)p1; na3 = *(const bf16x8*)(p1 + 32);
      }
      f32x4 acc0 = {0.f,0.f,0.f,0.f}, acc1 = {0.f,0.f,0.f,0.f};
      acc0 = MFMA16(ka0, qb0, acc0); acc0 = MFMA16(ka1, qb1, acc0);
      acc1 = MFMA16(ka2, qb0, acc1); acc1 = MFMA16(ka3, qb1, acc1);
      float sv[8]; float mloc = -INFINITY;
#pragma unroll
      for (int x = 0; x < 8; ++x) {
        float s = ((x < 4) ? acc0[x & 3] : acc1[x & 3]) * 0.125f;
        sv[x] = s;
        int j = j0 + ((x >> 2) << 4) + lg * 4 + (x & 3);
        mloc = fmaxf(mloc, (j <= i) ? s : -INFINITY);
      }
      mloc = fmaxf(mloc, __shfl_xor(mloc, 16, 64));
      mloc = fmaxf(mloc, __shfl_xor(mloc, 32, 64));
      float mn = fmaxf(m1w, mloc);
      float sc = __expf(m1w - mn);
      float ls = 0.f;
#pragma unroll
      for (int x = 0; x < 8; ++x) {
        int j = j0 + ((x >> 2) << 4) + lg * 4 + (x & 3);
        ls += (j <= i) ? __expf(sv[x] - mn) : 0.f;
      }
      ls += __shfl_xor(ls, 16, 64);
      ls += __shfl_xor(ls, 32, 64);
      denw = denw * sc + ls;
      m1w = mn;
      if (pf) { ka0 = na0; ka1 = na1; ka2 = na2; ka3 = na3; }
    }
    if (lg == 0) { sm1[w][li] = m1w; sden[w][li] = denw; }
    __syncthreads();

    const float gm0 = sm1[0][li], gm1v = sm1[1][li], gm2v = sm1[2][li], gm3v = sm1[3][li];
    const float m1 = fmaxf(fmaxf(gm0, gm1v), fmaxf(gm2v, gm3v));
    const float d0 = sden[0][li] * __expf(gm0 - m1);
    const float d1 = sden[1][li] * __expf(gm1v - m1);
    const float d2 = sden[2][li] * __expf(gm2v - m1);
    const float d3 = sden[3][li] * __expf(gm3v - m1);
    const float den = d0 + d1 + d2 + d3;
    const float inv1 = 1.f / den;
    float cum = 0.f;
    if (w > 0) cum += d0;
    if (w > 1) cum += d1;
    if (w > 2) cum += d2;

    // ---------------- pass 2: decay + online softmax-2 + PV ----------------
    float m2w = -INFINITY, l2w = 0.f;
    f32x4 o0 = {0.f,0.f,0.f,0.f}, o1 = {0.f,0.f,0.f,0.f};
    f32x4 o2 = {0.f,0.f,0.f,0.f}, o3 = {0.f,0.f,0.f,0.f};
    bf16x8 va0, va1, va2, va3;
    if (tb < te) {
      const int jb = tb * 32;
      const unsigned short* p0 = Kp + (size_t)(jb + li) * DK_ + lg * 8;
      const unsigned short* p1 = Kp + (size_t)(jb + 16 + li) * DK_ + lg * 8;
      ka0 = *(const bf16x8*)p0; ka1 = *(const bf16x8*)(p0 + 32);
      ka2 = *(const bf16x8*)p1; ka3 = *(const bf16x8*)(p1 + 32);
      va0 = *(const bf16x8*)(Vp + (size_t)li * S_ + jb + lg * 8);
      va1 = *(const bf16x8*)(Vp + (size_t)(16 + li) * S_ + jb + lg * 8);
      va2 = *(const bf16x8*)(Vp + (size_t)(32 + li) * S_ + jb + lg * 8);
      va3 = *(const bf16x8*)(Vp + (size_t)(48 + li) * S_ + jb + lg * 8);
    }
    for (int t = tb; t < te; ++t) {
      const int j0 = t * 32;
      const bool pf = (t + 1 < te);
      bf16x8 na0, na1, na2, na3, nv0, nv1, nv2, nv3;
      if (pf) {
        const int j1 = j0 + 32;
        const unsigned short* p0 = Kp + (size_t)(j1 + li) * DK_ + lg * 8;
        const unsigned short* p1 = Kp + (size_t)(j1 + 16 + li) * DK_ + lg * 8;
        na0 = *(const bf16x8*)p0; na1 = *(const bf16x8*)(p0 + 32);
        na2 = *(const bf16x8*)p1; na3 = *(const bf16x8*)(p1 + 32);
        nv0 = *(const bf16x8*)(Vp + (size_t)li * S_ + j1 + lg * 8);
        nv1 = *(const bf16x8*)(Vp + (size_t)(16 + li) * S_ + j1 + lg * 8);
        nv2 = *(const bf16x8*)(Vp + (size_t)(32 + li) * S_ + j1 + lg * 8);
        nv3 = *(const bf16x8*)(Vp + (size_t)(48 + li) * S_ + j1 + lg * 8);
      }
      f32x4 acc0 = {0.f,0.f,0.f,0.f}, acc1 = {0.f,0.f,0.f,0.f};
      acc0 = MFMA16(ka0, qb0, acc0); acc0 = MFMA16(ka1, qb1, acc0);
      acc1 = MFMA16(ka2, qb0, acc1); acc1 = MFMA16(ka3, qb1, acc1);

      float sv[8], ev[8]; bool uv[8];
#pragma unroll
      for (int x = 0; x < 8; ++x) {
        float s = ((x < 4) ? acc0[x & 3] : acc1[x & 3]) * 0.125f;
        sv[x] = s;
        int j = j0 + ((x >> 2) << 4) + lg * 4 + (x & 3);
        uv[x] = (j <= i);
        ev[x] = uv[x] ? __expf(s - m1) : 0.f;
      }
      float L0 = ev[0] + ev[1] + ev[2] + ev[3];
      float L1 = ev[4] + ev[5] + ev[6] + ev[7];
      float v0 = L0;
      { float tt = __shfl_up(v0, 16, 64); if (lg >= 1) v0 += tt;
        tt = __shfl_up(v0, 32, 64); if (lg >= 2) v0 += tt; }
      float tot0 = __shfl(v0, li + 48, 64);
      float v1 = L1;
      { float tt = __shfl_up(v1, 16, 64); if (lg >= 1) v1 += tt;
        tt = __shfl_up(v1, 32, 64); if (lg >= 2) v1 += tt; }
      float tot1 = __shfl(v1, li + 48, 64);
      float base0 = cum + (v0 - L0);
      float base1 = cum + tot0 + (v1 - L1);
      cum += tot0 + tot1;

      float s2[8]; float run = base0;
#pragma unroll
      for (int x = 0; x < 8; ++x) {
        if (x == 4) run = base1;
        run += ev[x];
        int j = j0 + ((x >> 2) << 4) + lg * 4 + (x & 3);
        float rem = fmaxf(1.f - run * inv1, 0.f);
        float dist = sqrtf(fmaxf(rem * (float)(i - j), 0.f));
        float te2 = fminf(fmaxf(__expf(dist * g), 1e-5f), 1e5f);
        s2[x] = uv[x] ? te2 * sv[x] : -INFINITY;
      }
      float mloc = s2[0];
#pragma unroll
      for (int x = 1; x < 8; ++x) mloc = fmaxf(mloc, s2[x]);
      mloc = fmaxf(mloc, __shfl_xor(mloc, 16, 64));
      mloc = fmaxf(mloc, __shfl_xor(mloc, 32, 64));
      float mn = fmaxf(m2w, mloc);
      float f = __expf(m2w - mn);
      float p[8]; float ls = 0.f;
#pragma unroll
      for (int x = 0; x < 8; ++x) { p[x] = __expf(s2[x] - mn); ls += p[x]; }
      ls += __shfl_xor(ls, 16, 64);
      ls += __shfl_xor(ls, 32, 64);
      l2w = l2w * f + ls;
      m2w = mn;
      o0 *= f; o1 *= f; o2 *= f; o3 *= f;

      { uint2 w0v = { pack2(p[0], p[1]), pack2(p[2], p[3]) };
        uint2 w1v = { pack2(p[4], p[5]), pack2(p[6], p[7]) };
        *(uint2*)&P[w][li][lg * 4] = w0v;
        *(uint2*)&P[w][li][16 + lg * 4] = w1v; }
      bf16x8 pb = *(const bf16x8*)&P[w][li][lg * 8];
      o0 = MFMA16(va0, pb, o0);
      o1 = MFMA16(va1, pb, o1);
      o2 = MFMA16(va2, pb, o2);
      o3 = MFMA16(va3, pb, o3);

      if (pf) { ka0 = na0; ka1 = na1; ka2 = na2; ka3 = na3;
                va0 = nv0; va1 = nv1; va2 = nv2; va3 = nv3; }
    }

    // ---------------- merge 4 chunk partials ----------------
    if (lg == 0) { sm2[w][li] = m2w; sl2[w][li] = l2w; }
    {
      f32x4 oo[4] = { o0, o1, o2, o3 };
#pragma unroll
      for (int db = 0; db < 4; ++db)
#pragma unroll
        for (int e = 0; e < 4; ++e)
          Obuf[w][lane][db * 4 + e] = oo[db][e];
    }
    __syncthreads();
    if (w == 0) {
      const float q0 = sm2[0][li], q1 = sm2[1][li], q2 = sm2[2][li], q3 = sm2[3][li];
      const float m2 = fmaxf(fmaxf(q0, q1), fmaxf(q2, q3));
      const float f0 = __expf(q0 - m2), f1 = __expf(q1 - m2);
      const float f2 = __expf(q2 - m2), f3 = __expf(q3 - m2);
      const float l2 = sl2[0][li] * f0 + sl2[1][li] * f1 + sl2[2][li] * f2 + sl2[3][li] * f3;
      const float z = (i == 0) ? 0.f : (1.f / l2);
      unsigned short* dst = out_pre + ((size_t)(b * S_ + i)) * D_ + h * DK_;
#pragma unroll
      for (int db = 0; db < 4; ++db) {
        float vo[4];
#pragma unroll
        for (int e = 0; e < 4; ++e)
          vo[e] = (Obuf[0][lane][db * 4 + e] * f0 + Obuf[1][lane][db * 4 + e] * f1 +
                   Obuf[2][lane][db * 4 + e] * f2 + Obuf[3][lane][db * 4 + e] * f3) * z;
        ushort4 y = { f2bf(vo[0]), f2bf(vo[1]), f2bf(vo[2]), f2bf(vo[3]) };
        *(ushort4*)&dst[db * 16 + lg * 4] = y;
      }
    }
  }
}

// ---------------------------------------------------------------------------
extern "C" void kernel_launch(void* const* d_in, const int* in_sizes, int n_in,
                              void* d_out, int out_size, void* d_ws, size_t ws_size,
                              hipStream_t stream) {
  const float* q  = (const float*)d_in[0];
  const float* k  = (const float*)d_in[1];
  const float* v  = (const float*)d_in[2];
  const float* Wq = (const float*)d_in[5];
  const float* bq = (const float*)d_in[6];
  const float* Wk = (const float*)d_in[7];
  const float* bk = (const float*)d_in[8];
  const float* Wv = (const float*)d_in[9];
  const float* bv = (const float*)d_in[10];
  const float* Wo = (const float*)d_in[11];
  const float* bo = (const float*)d_in[12];
  const float* gammas = (const float*)d_in[13];
  float* out = (float*)d_out;

  float* cs = (float*)d_ws;
  unsigned short* Abf  = (unsigned short*)(cs + (size_t)S_ * 32 * 2);
  unsigned short* Wbf  = Abf + (size_t)3 * 4096 * 512;
  unsigned short* Qbf  = Wbf + (size_t)4 * 512 * 512;
  unsigned short* Kbf  = Qbf + (size_t)B_ * H_ * S_ * DK_;
  unsigned short* Vtbf = Kbf + (size_t)B_ * H_ * S_ * DK_;
  unsigned short* out_pre = Vtbf + (size_t)B_ * H_ * S_ * DK_;

  rope_table_k<<<(S_ * 32 + 255) / 256, 256, 0, stream>>>(cs);
  cvt3_k<<<6144, 256, 0, stream>>>(q, k, v, Abf);
  cvt4_k<<<1024, 256, 0, stream>>>(Wq, Wk, Wv, Wo, Wbf);

  const size_t nA = (size_t)4096 * 512;
  const size_t nW = (size_t)512 * 512;
  dim3 gg(8, 32);   // N/64 x M/128
  gemm2<<<gg, 256, 0, stream>>>(Abf,          Wbf,          bq, Qbf,  cs, 1);
  gemm2<<<gg, 256, 0, stream>>>(Abf + nA,     Wbf + nW,     bk, Kbf,  cs, 1);
  gemm2<<<gg, 256, 0, stream>>>(Abf + 2 * nA, Wbf + 2 * nW, bv, Vtbf, cs, 2);

  attn3<<<dim3(64, B_ * H_), 256, 0, stream>>>(Qbf, Kbf, Vtbf, gammas, out_pre);

  gemm2<<<gg, 256, 0, stream>>>(out_pre, Wbf + 3 * nW, bo, out, cs, 0);
}

// Round 11
// 256.733 us; speedup vs baseline: 7.4228x; 1.0548x over previous
//
#include <hip/hip_runtime.h>
#include <math.h>

#define B_ 2
#define S_ 2048
#define D_ 512
#define H_ 8
#define DK_ 64

typedef __attribute__((ext_vector_type(8))) short bf16x8;
typedef __attribute__((ext_vector_type(4))) float f32x4;

#define MFMA16(A, Bv, C) __builtin_amdgcn_mfma_f32_16x16x32_bf16(A, Bv, C, 0, 0, 0)
#define EXP2(x) __builtin_amdgcn_exp2f(x)
#define LOG2E 1.4426950408889634f

__device__ inline unsigned short f2bf(float x) {
  unsigned u = __float_as_uint(x);
  unsigned r = (u + 0x7fffu + ((u >> 16) & 1u)) >> 16;
  return (unsigned short)r;
}
__device__ inline unsigned pack2(float a, float b) {
  return (unsigned)f2bf(a) | ((unsigned)f2bf(b) << 16);
}
__device__ __forceinline__ void gload16(const void* g, void* l) {
  __builtin_amdgcn_global_load_lds((const __attribute__((address_space(1))) unsigned*)g,
                                   (__attribute__((address_space(3))) unsigned*)l, 16, 0, 0);
}

// ---------------------------------------------------------------------------
// RoPE cos/sin table
// ---------------------------------------------------------------------------
__global__ void rope_table_k(float* cs) {
  int idx = blockIdx.x * blockDim.x + threadIdx.x;
  if (idx >= S_ * 32) return;
  int s = idx >> 5, i = idx & 31;
  float invf = powf(10000.0f, -(float)(2 * i) / 64.0f);
  float ang = (float)s * invf;
  double a = (double)ang;
  cs[idx * 2]     = (float)cos(a);
  cs[idx * 2 + 1] = (float)sin(a);
}

// ---------------------------------------------------------------------------
// f32 -> bf16 converters
// ---------------------------------------------------------------------------
__global__ __launch_bounds__(256)
void cvt3_k(const float* __restrict__ a, const float* __restrict__ b,
            const float* __restrict__ c, unsigned short* __restrict__ dst) {
  size_t idx = ((size_t)blockIdx.x * 256 + threadIdx.x) * 4;
  const size_t per = (size_t)4096 * 512;
  const float* src; size_t r;
  if (idx < per)            { src = a; r = idx; }
  else if (idx < 2 * per)   { src = b; r = idx - per; }
  else                      { src = c; r = idx - 2 * per; }
  float4 x = *(const float4*)(src + r);
  ushort4 y = { f2bf(x.x), f2bf(x.y), f2bf(x.z), f2bf(x.w) };
  *(ushort4*)(dst + idx) = y;
}
__global__ __launch_bounds__(256)
void cvt4_k(const float* __restrict__ a, const float* __restrict__ b,
            const float* __restrict__ c, const float* __restrict__ d,
            unsigned short* __restrict__ dst) {
  size_t idx = ((size_t)blockIdx.x * 256 + threadIdx.x) * 4;
  const size_t per = (size_t)512 * 512;
  const float* src; size_t r;
  if (idx < per)            { src = a; r = idx; }
  else if (idx < 2 * per)   { src = b; r = idx - per; }
  else if (idx < 3 * per)   { src = c; r = idx - 2 * per; }
  else                      { src = d; r = idx - 3 * per; }
  float4 x = *(const float4*)(src + r);
  ushort4 y = { f2bf(x.x), f2bf(x.y), f2bf(x.z), f2bf(x.w) };
  *(ushort4*)(dst + idx) = y;
}

// ---------------------------------------------------------------------------
// 64x64 bf16 GEMM core: C = A(Mx512) * W(512x512)^T + bias
// BK=64, 4 waves (wave w owns cols w*16..+15), double-buffered LDS,
// global_load_lds w/ both-sides XOR-16B swizzle.
// ---------------------------------------------------------------------------
__device__ __forceinline__ void gemm64_core(
    const unsigned short* __restrict__ A, const unsigned short* __restrict__ W,
    const float* __restrict__ bias, void* __restrict__ Cout,
    const float* __restrict__ cs, int mode,
    unsigned short (*As)[64 * 64], unsigned short (*Ws)[64 * 64]) {
  const int bm = blockIdx.y * 64, bn = blockIdx.x * 64;
  const int tid = threadIdx.x, w = tid >> 6, lane = tid & 63;
  const int li = lane & 15, lg = lane >> 4;
  f32x4 acc[4] = {};

  const char* Ab0 = (const char*)A + (size_t)bm * 1024;
  const char* Wb0 = (const char*)W + (size_t)bn * 1024;

  auto stage = [&](int buf, int t) {
    const char* Ab = Ab0 + t * 128;
    const char* Wb = Wb0 + t * 128;
    char* AsB = (char*)&As[buf][0];
    char* WsB = (char*)&Ws[buf][0];
#pragma unroll
    for (int rr = 0; rr < 2; ++rr) {
      const int rowbase = rr * 32 + w * 8;
      const int row = rowbase + (lane >> 3);
      const int sc_ = ((lane & 7) ^ (row & 7)) << 4;
      gload16(Ab + (size_t)row * 1024 + sc_, AsB + rowbase * 128);
      gload16(Wb + (size_t)row * 1024 + sc_, WsB + rowbase * 128);
    }
  };

  stage(0, 0);
  int cur = 0;
  for (int t = 0; t < 8; ++t) {
    __syncthreads();
    if (t < 7) stage(cur ^ 1, t + 1);
#pragma unroll
    for (int kk = 0; kk < 2; ++kk) {
      const int chunk = kk * 4 + lg;
      const int brow = w * 16 + li;
      bf16x8 bf = *(const bf16x8*)&Ws[cur][brow * 64 + ((chunk ^ (brow & 7)) << 3)];
#pragma unroll
      for (int mt = 0; mt < 4; ++mt) {
        const int arow = mt * 16 + li;
        bf16x8 af = *(const bf16x8*)&As[cur][arow * 64 + ((chunk ^ (arow & 7)) << 3)];
        acc[mt] = MFMA16(af, bf, acc[mt]);
      }
    }
    cur ^= 1;
  }

  const int n = bn + w * 16 + li;
  const float bv = bias[n];
  if (mode == 0) {
    float* C = (float*)Cout;
#pragma unroll
    for (int mt = 0; mt < 4; ++mt)
#pragma unroll
      for (int r = 0; r < 4; ++r) {
        int m = bm + mt * 16 + lg * 4 + r;
        C[(size_t)m * 512 + n] = acc[mt][r] + bv;
      }
  } else if (mode == 1) {
    unsigned short* C = (unsigned short*)Cout;
    const int d = n & 63, hh = n >> 6, p = d >> 1;
#pragma unroll
    for (int mt = 0; mt < 4; ++mt)
#pragma unroll
      for (int r = 0; r < 4; ++r) {
        int m = bm + mt * 16 + lg * 4 + r;
        int bb = m >> 11, sp = m & (S_ - 1);
        float val = acc[mt][r] + bv;
        float other = __shfl_xor(val, 1, 64);
        const float* cp = cs + ((size_t)sp * 32 + p) * 2;
        float cc = cp[0], sn = cp[1];
        float y = (d & 1) ? (val * cc + other * sn) : (val * cc - other * sn);
        C[(((size_t)bb * H_ + hh) * S_ + sp) * DK_ + d] = f2bf(y);
      }
  } else {
    unsigned short* C = (unsigned short*)Cout;
    const int d = n & 63, hh = n >> 6;
#pragma unroll
    for (int mt = 0; mt < 4; ++mt) {
      int m0 = bm + mt * 16 + lg * 4;
      int bb = m0 >> 11, sp0 = m0 & (S_ - 1);
      ushort4 y = { f2bf(acc[mt][0] + bv), f2bf(acc[mt][1] + bv),
                    f2bf(acc[mt][2] + bv), f2bf(acc[mt][3] + bv) };
      *(ushort4*)&C[(((size_t)bb * H_ + hh) * DK_ + d) * S_ + sp0] = y;
    }
  }
}

// Batched Q/K/V projections: blockIdx.z selects which GEMM (3x occupancy)
__global__ __launch_bounds__(256)
void gemm_proj(const unsigned short* __restrict__ Abf,
               const unsigned short* __restrict__ Wbf,
               const float* __restrict__ bq, const float* __restrict__ bk,
               const float* __restrict__ bv,
               unsigned short* __restrict__ Qbf, unsigned short* __restrict__ Kbf,
               unsigned short* __restrict__ Vtbf, const float* __restrict__ cs) {
  __shared__ __align__(16) unsigned short As[2][64 * 64];
  __shared__ __align__(16) unsigned short Ws[2][64 * 64];
  const int z = blockIdx.z;
  const size_t nA = (size_t)4096 * 512, nW = (size_t)512 * 512;
  const unsigned short* A = Abf + (size_t)z * nA;
  const unsigned short* W = Wbf + (size_t)z * nW;
  const float* bias = (z == 0) ? bq : (z == 1) ? bk : bv;
  void* out = (z == 0) ? (void*)Qbf : (z == 1) ? (void*)Kbf : (void*)Vtbf;
  const int mode = (z == 2) ? 2 : 1;
  gemm64_core(A, W, bias, out, cs, mode, As, Ws);
}

__global__ __launch_bounds__(256)
void gemm_one(const unsigned short* __restrict__ A, const unsigned short* __restrict__ W,
              const float* __restrict__ bias, float* __restrict__ out) {
  __shared__ __align__(16) unsigned short As[2][64 * 64];
  __shared__ __align__(16) unsigned short Ws[2][64 * 64];
  gemm64_core(A, W, bias, out, nullptr, 0, As, Ws);
}

// ---------------------------------------------------------------------------
// Split-K attention (exp2 space): block handles query tiles (127-bx, bx);
// 4 waves split keys; cumsum prefix from pass-1 partials.
// ---------------------------------------------------------------------------
__global__ __launch_bounds__(256)
void attn3(const unsigned short* __restrict__ Qbf,
           const unsigned short* __restrict__ Kbf,
           const unsigned short* __restrict__ Vtbf,
           const float* __restrict__ gammas,
           unsigned short* __restrict__ out_pre) {
  const int bx = (int)blockIdx.x;           // 0..63
  const int bh = blockIdx.y;
  const int h = bh & (H_ - 1), b = bh >> 3;
  const int tid = threadIdx.x;
  const int w = tid >> 6, lane = tid & 63;
  const int li = lane & 15, lg = lane >> 4;
  const float SCL = 0.125f * LOG2E;

  __shared__ __align__(16) unsigned short P[4][16][40];
  __shared__ float sm1[4][16], sden[4][16], sm2[4][16], sl2[4][16];
  __shared__ float Obuf[4][64][17];

  const unsigned short* Qp = Qbf + (size_t)bh * (S_ * DK_);
  const unsigned short* Kp = Kbf + (size_t)bh * (S_ * DK_);
  const unsigned short* Vp = Vtbf + (size_t)bh * (DK_ * S_);

  for (int half = 0; half < 2; ++half) {
    const int qt = half ? bx : (127 - bx);
    const int i0 = qt * 16;
    const int i = i0 + li;

    bf16x8 qb0 = *(const bf16x8*)(Qp + (size_t)i * DK_ + lg * 8);
    bf16x8 qb1 = *(const bf16x8*)(Qp + (size_t)i * DK_ + 32 + lg * 8);

    const int ntile = (i0 >> 5) + 1;
    const int nt4 = (ntile + 3) >> 2;
    const int tb = (w * nt4 < ntile) ? w * nt4 : ntile;
    const int te = (tb + nt4 < ntile) ? tb + nt4 : ntile;

    const float g2 = -log1pf(__expf(gammas[h * S_ + i])) * LOG2E;

    // ---------------- pass 1 ----------------
    float m1w = -INFINITY, denw = 0.f;
    bf16x8 ka0, ka1, ka2, ka3;
    if (tb < te) {
      const int jb = tb * 32;
      const unsigned short* p0 = Kp + (size_t)(jb + li) * DK_ + lg * 8;
      const unsigned short* p1 = Kp + (size_t)(jb + 16 + li) * DK_ + lg * 8;
      ka0 = *(const bf16x8*)p0; ka1 = *(const bf16x8*)(p0 + 32);
      ka2 = *(const bf16x8*)p1; ka3 = *(const bf16x8*)(p1 + 32);
    }
    for (int t = tb; t < te; ++t) {
      const int j0 = t * 32;
      const bool pf = (t + 1 < te);
      bf16x8 na0, na1, na2, na3;
      if (pf) {
        const unsigned short* p0 = Kp + (size_t)(j0 + 32 + li) * DK_ + lg * 8;
        const unsigned short* p1 = Kp + (size_t)(j0 + 48 + li) * DK_ + lg * 8;
        na0 = *(const bf16x8*)p0; na1 = *(const bf16x8*)(p0 + 32);
        na2 = *(const bf16x8*)p1; na3 = *(const bf16x8*)(p1 + 32);
      }
      f32x4 acc0 = {0.f,0.f,0.f,0.f}, acc1 = {0.f,0.f,0.f,0.f};
      acc0 = MFMA16(ka0, qb0, acc0); acc0 = MFMA16(ka1, qb1, acc0);
      acc1 = MFMA16(ka2, qb0, acc1); acc1 = MFMA16(ka3, qb1, acc1);
      float sv[8]; float mloc = -INFINITY;
#pragma unroll
      for (int x = 0; x < 8; ++x) {
        float s = ((x < 4) ? acc0[x & 3] : acc1[x & 3]) * SCL;
        sv[x] = s;
        int j = j0 + ((x >> 2) << 4) + lg * 4 + (x & 3);
        mloc = fmaxf(mloc, (j <= i) ? s : -INFINITY);
      }
      mloc = fmaxf(mloc, __shfl_xor(mloc, 16, 64));
      mloc = fmaxf(mloc, __shfl_xor(mloc, 32, 64));
      float mn = fmaxf(m1w, mloc);
      float sc = EXP2(m1w - mn);
      float ls = 0.f;
#pragma unroll
      for (int x = 0; x < 8; ++x) {
        int j = j0 + ((x >> 2) << 4) + lg * 4 + (x & 3);
        ls += (j <= i) ? EXP2(sv[x] - mn) : 0.f;
      }
      ls += __shfl_xor(ls, 16, 64);
      ls += __shfl_xor(ls, 32, 64);
      denw = denw * sc + ls;
      m1w = mn;
      if (pf) { ka0 = na0; ka1 = na1; ka2 = na2; ka3 = na3; }
    }
    if (lg == 0) { sm1[w][li] = m1w; sden[w][li] = denw; }
    __syncthreads();

    const float gm0 = sm1[0][li], gm1v = sm1[1][li], gm2v = sm1[2][li], gm3v = sm1[3][li];
    const float m1 = fmaxf(fmaxf(gm0, gm1v), fmaxf(gm2v, gm3v));
    const float d0 = sden[0][li] * EXP2(gm0 - m1);
    const float d1 = sden[1][li] * EXP2(gm1v - m1);
    const float d2 = sden[2][li] * EXP2(gm2v - m1);
    const float d3 = sden[3][li] * EXP2(gm3v - m1);
    const float den = d0 + d1 + d2 + d3;
    const float inv1 = 1.f / den;
    float cum = 0.f;
    if (w > 0) cum += d0;
    if (w > 1) cum += d1;
    if (w > 2) cum += d2;

    // ---------------- pass 2 ----------------
    float m2w = -INFINITY, l2w = 0.f;
    f32x4 o0 = {0.f,0.f,0.f,0.f}, o1 = {0.f,0.f,0.f,0.f};
    f32x4 o2 = {0.f,0.f,0.f,0.f}, o3 = {0.f,0.f,0.f,0.f};
    bf16x8 va0, va1, va2, va3;
    if (tb < te) {
      const int jb = tb * 32;
      const unsigned short* p0 = Kp + (size_t)(jb + li) * DK_ + lg * 8;
      const unsigned short* p1 = Kp + (size_t)(jb + 16 + li) * DK_ + lg * 8;
      ka0 = *(const bf16x8*)p0; ka1 = *(const bf16x8*)(p0 + 32);
      ka2 = *(const bf16x8*)p1; ka3 = *(const bf16x8*)(p1 + 32);
      va0 = *(const bf16x8*)(Vp + (size_t)li * S_ + jb + lg * 8);
      va1 = *(const bf16x8*)(Vp + (size_t)(16 + li) * S_ + jb + lg * 8);
      va2 = *(const bf16x8*)(Vp + (size_t)(32 + li) * S_ + jb + lg * 8);
      va3 = *(const bf16x8*)(Vp + (size_t)(48 + li) * S_ + jb + lg * 8);
    }
    for (int t = tb; t < te; ++t) {
      const int j0 = t * 32;
      const bool pf = (t + 1 < te);
      bf16x8 na0, na1, na2, na3, nv0, nv1, nv2, nv3;
      if (pf) {
        const int j1 = j0 + 32;
        const unsigned short* p0 = Kp + (size_t)(j1 + li) * DK_ + lg * 8;
        const unsigned short* p1 = Kp + (size_t)(j1 + 16 + li) * DK_ + lg * 8;
        na0 = *(const bf16x8*)p0; na1 = *(const bf16x8*)(p0 + 32);
        na2 = *(const bf16x8*)p1; na3 = *(const bf16x8*)(p1 + 32);
        nv0 = *(const bf16x8*)(Vp + (size_t)li * S_ + j1 + lg * 8);
        nv1 = *(const bf16x8*)(Vp + (size_t)(16 + li) * S_ + j1 + lg * 8);
        nv2 = *(const bf16x8*)(Vp + (size_t)(32 + li) * S_ + j1 + lg * 8);
        nv3 = *(const bf16x8*)(Vp + (size_t)(48 + li) * S_ + j1 + lg * 8);
      }
      f32x4 acc0 = {0.f,0.f,0.f,0.f}, acc1 = {0.f,0.f,0.f,0.f};
      acc0 = MFMA16(ka0, qb0, acc0); acc0 = MFMA16(ka1, qb1, acc0);
      acc1 = MFMA16(ka2, qb0, acc1); acc1 = MFMA16(ka3, qb1, acc1);

      float sv[8], ev[8]; bool uv[8];
#pragma unroll
      for (int x = 0; x < 8; ++x) {
        float s = ((x < 4) ? acc0[x & 3] : acc1[x & 3]) * SCL;
        sv[x] = s;
        int j = j0 + ((x >> 2) << 4) + lg * 4 + (x & 3);
        uv[x] = (j <= i);
        ev[x] = uv[x] ? EXP2(s - m1) : 0.f;
      }
      float L0 = ev[0] + ev[1] + ev[2] + ev[3];
      float L1 = ev[4] + ev[5] + ev[6] + ev[7];
      float v0 = L0;
      { float tt = __shfl_up(v0, 16, 64); if (lg >= 1) v0 += tt;
        tt = __shfl_up(v0, 32, 64); if (lg >= 2) v0 += tt; }
      float tot0 = __shfl(v0, li + 48, 64);
      float v1 = L1;
      { float tt = __shfl_up(v1, 16, 64); if (lg >= 1) v1 += tt;
        tt = __shfl_up(v1, 32, 64); if (lg >= 2) v1 += tt; }
      float tot1 = __shfl(v1, li + 48, 64);
      float base0 = cum + (v0 - L0);
      float base1 = cum + tot0 + (v1 - L1);
      cum += tot0 + tot1;

      float s2[8]; float run = base0;
#pragma unroll
      for (int x = 0; x < 8; ++x) {
        if (x == 4) run = base1;
        run += ev[x];
        int j = j0 + ((x >> 2) << 4) + lg * 4 + (x & 3);
        float rem = fmaxf(1.f - run * inv1, 0.f);
        float dist = sqrtf(fmaxf(rem * (float)(i - j), 0.f));
        float te2 = fminf(fmaxf(EXP2(dist * g2), 1e-5f), 1e5f);
        s2[x] = uv[x] ? te2 * sv[x] : -INFINITY;
      }
      float mloc = s2[0];
#pragma unroll
      for (int x = 1; x < 8; ++x) mloc = fmaxf(mloc, s2[x]);
      mloc = fmaxf(mloc, __shfl_xor(mloc, 16, 64));
      mloc = fmaxf(mloc, __shfl_xor(mloc, 32, 64));
      float mn = fmaxf(m2w, mloc);
      float f = EXP2(m2w - mn);
      float p[8]; float ls = 0.f;
#pragma unroll
      for (int x = 0; x < 8; ++x) { p[x] = EXP2(s2[x] - mn); ls += p[x]; }
      ls += __shfl_xor(ls, 16, 64);
      ls += __shfl_xor(ls, 32, 64);
      l2w = l2w * f + ls;
      m2w = mn;
      o0 *= f; o1 *= f; o2 *= f; o3 *= f;

      { uint2 w0v = { pack2(p[0], p[1]), pack2(p[2], p[3]) };
        uint2 w1v = { pack2(p[4], p[5]), pack2(p[6], p[7]) };
        *(uint2*)&P[w][li][lg * 4] = w0v;
        *(uint2*)&P[w][li][16 + lg * 4] = w1v; }
      bf16x8 pb = *(const bf16x8*)&P[w][li][lg * 8];
      o0 = MFMA16(va0, pb, o0);
      o1 = MFMA16(va1, pb, o1);
      o2 = MFMA16(va2, pb, o2);
      o3 = MFMA16(va3, pb, o3);

      if (pf) { ka0 = na0; ka1 = na1; ka2 = na2; ka3 = na3;
                va0 = nv0; va1 = nv1; va2 = nv2; va3 = nv3; }
    }

    // ---------------- merge (all 4 waves participate) ----------------
    if (lg == 0) { sm2[w][li] = m2w; sl2[w][li] = l2w; }
    {
      f32x4 oo[4] = { o0, o1, o2, o3 };
#pragma unroll
      for (int db = 0; db < 4; ++db)
#pragma unroll
        for (int e = 0; e < 4; ++e)
          Obuf[w][lane][db * 4 + e] = oo[db][e];
    }
    __syncthreads();
    {
      const float q0 = sm2[0][li], q1 = sm2[1][li], q2 = sm2[2][li], q3 = sm2[3][li];
      const float m2 = fmaxf(fmaxf(q0, q1), fmaxf(q2, q3));
      const float f0 = EXP2(q0 - m2), f1 = EXP2(q1 - m2);
      const float f2 = EXP2(q2 - m2), f3 = EXP2(q3 - m2);
      const float l2 = sl2[0][li] * f0 + sl2[1][li] * f1 + sl2[2][li] * f2 + sl2[3][li] * f3;
      const float z = (i == 0) ? 0.f : (1.f / l2);
      unsigned short* dst = out_pre + ((size_t)(b * S_ + i)) * D_ + h * DK_;
      float vo[4];
#pragma unroll
      for (int e = 0; e < 4; ++e)
        vo[e] = (Obuf[0][lane][w * 4 + e] * f0 + Obuf[1][lane][w * 4 + e] * f1 +
                 Obuf[2][lane][w * 4 + e] * f2 + Obuf[3][lane][w * 4 + e] * f3) * z;
      ushort4 y = { f2bf(vo[0]), f2bf(vo[1]), f2bf(vo[2]), f2bf(vo[3]) };
      *(ushort4*)&dst[w * 16 + lg * 4] = y;
    }
    __syncthreads();
  }
}

// ---------------------------------------------------------------------------
extern "C" void kernel_launch(void* const* d_in, const int* in_sizes, int n_in,
                              void* d_out, int out_size, void* d_ws, size_t ws_size,
                              hipStream_t stream) {
  const float* q  = (const float*)d_in[0];
  const float* k  = (const float*)d_in[1];
  const float* v  = (const float*)d_in[2];
  const float* Wq = (const float*)d_in[5];
  const float* bq = (const float*)d_in[6];
  const float* Wk = (const float*)d_in[7];
  const float* bk = (const float*)d_in[8];
  const float* Wv = (const float*)d_in[9];
  const float* bv = (const float*)d_in[10];
  const float* Wo = (const float*)d_in[11];
  const float* bo = (const float*)d_in[12];
  const float* gammas = (const float*)d_in[13];
  float* out = (float*)d_out;

  float* cs = (float*)d_ws;
  unsigned short* Abf  = (unsigned short*)(cs + (size_t)S_ * 32 * 2);
  unsigned short* Wbf  = Abf + (size_t)3 * 4096 * 512;
  unsigned short* Qbf  = Wbf + (size_t)4 * 512 * 512;
  unsigned short* Kbf  = Qbf + (size_t)B_ * H_ * S_ * DK_;
  unsigned short* Vtbf = Kbf + (size_t)B_ * H_ * S_ * DK_;
  unsigned short* out_pre = Vtbf + (size_t)B_ * H_ * S_ * DK_;

  rope_table_k<<<(S_ * 32 + 255) / 256, 256, 0, stream>>>(cs);
  cvt3_k<<<6144, 256, 0, stream>>>(q, k, v, Abf);
  cvt4_k<<<1024, 256, 0, stream>>>(Wq, Wk, Wv, Wo, Wbf);

  const size_t nW = (size_t)512 * 512;
  gemm_proj<<<dim3(8, 64, 3), 256, 0, stream>>>(Abf, Wbf, bq, bk, bv, Qbf, Kbf, Vtbf, cs);

  attn3<<<dim3(64, B_ * H_), 256, 0, stream>>>(Qbf, Kbf, Vtbf, gammas, out_pre);

  gemm_one<<<dim3(8, 64), 256, 0, stream>>>(out_pre, Wbf + 3 * nW, bo, out);
}